// Round 1
// baseline (2232.293 us; speedup 1.0000x reference)
//
#include <hip/hip_runtime.h>
#include <math.h>

#define NN 100000
#define EE 1600000
#define GG 64
#define DD 64
#define NF 128
#define EF 32
#define LVL 3
#define EPSBN 1e-5f

// ---------------- CSR build ----------------
__global__ void khist(const int* __restrict__ to, int* __restrict__ cnt) {
    int e = blockIdx.x * blockDim.x + threadIdx.x;
    if (e < EE) atomicAdd(&cnt[to[e]], 1);
}

__global__ void kscan(const int* __restrict__ cnt, int* __restrict__ row_ptr,
                      int* __restrict__ cursor) {
    __shared__ int part[1024];
    int t = threadIdx.x;
    const int C = (NN + 1023) / 1024;
    int lo = t * C, hi = min(lo + C, NN);
    int s = 0;
    for (int i = lo; i < hi; i++) s += cnt[i];
    part[t] = s;
    __syncthreads();
    for (int off = 1; off < 1024; off <<= 1) {
        int v = (t >= off) ? part[t - off] : 0;
        __syncthreads();
        part[t] += v;
        __syncthreads();
    }
    int run = (t == 0) ? 0 : part[t - 1];
    for (int i = lo; i < hi; i++) {
        row_ptr[i] = run;
        cursor[i] = run;
        run += cnt[i];
    }
    if (t == 0) row_ptr[NN] = part[1023];
}

__global__ void kreorder(const int* __restrict__ to, int* __restrict__ cursor,
                         int* __restrict__ eid) {
    int e = blockIdx.x * blockDim.x + threadIdx.x;
    if (e < EE) {
        int pos = atomicAdd(&cursor[to[e]], 1);
        eid[pos] = e;
    }
}

// ---------------- edge-feature pooling: pooled[n][j] = sum_{e: to==n} ef[e][j] ----------------
__global__ void kpool(const float* __restrict__ ef, const int* __restrict__ row_ptr,
                      const int* __restrict__ eid, float* __restrict__ pooled) {
    int tid0 = blockIdx.x * blockDim.x + threadIdx.x;
    int stride = gridDim.x * blockDim.x;
    for (int tid = tid0; tid < NN * EF; tid += stride) {
        int n = tid >> 5, j = tid & 31;
        int e0 = row_ptr[n], e1 = row_ptr[n + 1];
        float s = 0.f;
        for (int e = e0; e < e1; e++) s += ef[eid[e] * EF + j];
        pooled[tid] = s;
    }
}

// ---------------- h0 = relu(node_feat@W + b + emb[nvi] + pooled@We + deg*be); stats ----------------
__global__ void kh0(const float* __restrict__ nf, const float* __restrict__ W,
                    const float* __restrict__ b, const float* __restrict__ emb,
                    const int* __restrict__ nvi, const float* __restrict__ pooled,
                    const int* __restrict__ row_ptr, const float* __restrict__ We,
                    const float* __restrict__ be, float* __restrict__ x,
                    float* __restrict__ stats) {
    int t = threadIdx.x;
    int d = t & 63;
    float ssum = 0.f, ssq = 0.f;
    for (int n = blockIdx.x * 4 + (t >> 6); n < NN; n += gridDim.x * 4) {
        float acc = b[d] + emb[nvi[n] * DD + d];
        const float4* a4 = (const float4*)(nf + (size_t)n * NF);
#pragma unroll
        for (int k4 = 0; k4 < NF / 4; k4++) {
            float4 a = a4[k4];
            int k = k4 * 4;
            acc += a.x * W[(k + 0) * DD + d] + a.y * W[(k + 1) * DD + d] +
                   a.z * W[(k + 2) * DD + d] + a.w * W[(k + 3) * DD + d];
        }
        const float4* p4 = (const float4*)(pooled + (size_t)n * EF);
#pragma unroll
        for (int j4 = 0; j4 < EF / 4; j4++) {
            float4 p = p4[j4];
            int j = j4 * 4;
            acc += p.x * We[(j + 0) * DD + d] + p.y * We[(j + 1) * DD + d] +
                   p.z * We[(j + 2) * DD + d] + p.w * We[(j + 3) * DD + d];
        }
        float deg = (float)(row_ptr[n + 1] - row_ptr[n]);
        acc += deg * be[d];
        acc = fmaxf(acc, 0.f);
        x[(size_t)n * DD + d] = acc;
        ssum += acc;
        ssq += acc * acc;
    }
    __shared__ float sb[256], sq[256];
    sb[t] = ssum;
    sq[t] = ssq;
    __syncthreads();
    if (t < 64) {
        atomicAdd(&stats[t], sb[t] + sb[t + 64] + sb[t + 128] + sb[t + 192]);
        atomicAdd(&stats[64 + t], sq[t] + sq[t + 64] + sq[t + 128] + sq[t + 192]);
    }
}

// ---------------- BN finalize: scale/shift from sums; re-zero sums ----------------
__global__ void kfin(float* __restrict__ stats, const float* __restrict__ g,
                     const float* __restrict__ b) {
    int t = threadIdx.x;  // 64
    float mean = stats[t] * (1.0f / NN);
    float var = stats[64 + t] * (1.0f / NN) - mean * mean;
    float rstd = rsqrtf(fmaxf(var, 0.f) + EPSBN);
    float sc = g[t] * rstd;
    stats[128 + t] = sc;
    stats[192 + t] = b[t] - mean * sc;
    stats[t] = 0.f;
    stats[64 + t] = 0.f;
}

// ---------------- normalize: out[i] = x[i]*scale[d] + shift[d] ----------------
__global__ void knorm(const float* __restrict__ x, const float* __restrict__ stats,
                      float* __restrict__ h) {
    int i0 = blockIdx.x * blockDim.x + threadIdx.x;
    int str = gridDim.x * blockDim.x;
    for (int i = i0; i < NN * DD; i += str) {
        int d = i & 63;
        h[i] = x[i] * stats[128 + d] + stats[192 + d];
    }
}

// ---------------- message passing gather: agg[n][d] = sum_{e in CSR[n]} h[from[e]][d] ----------------
__global__ void kmsg(const float* __restrict__ h, const int* __restrict__ row_ptr,
                     const int* __restrict__ eid, const int* __restrict__ efrom,
                     float* __restrict__ agg) {
    int lane = threadIdx.x & 63;
    int wid = threadIdx.x >> 6;
    for (int n = blockIdx.x * 4 + wid; n < NN; n += gridDim.x * 4) {
        int e0 = row_ptr[n], e1 = row_ptr[n + 1];
        float acc = 0.f;
        int e = e0;
        for (; e + 1 < e1; e += 2) {
            int s0 = efrom[eid[e]];
            int s1 = efrom[eid[e + 1]];
            acc += h[(size_t)s0 * DD + lane];
            acc += h[(size_t)s1 * DD + lane];
        }
        if (e < e1) acc += h[(size_t)efrom[eid[e]] * DD + lane];
        agg[(size_t)n * DD + lane] = acc;
    }
}

// ---------------- merged = relu(agg@cW + cb + pooled@We + deg*be); stats ----------------
__global__ void kmerge(const float* __restrict__ agg, const float* __restrict__ cW,
                       const float* __restrict__ cb, const float* __restrict__ pooled,
                       const float* __restrict__ We, const float* __restrict__ be,
                       const int* __restrict__ row_ptr, float* __restrict__ x,
                       float* __restrict__ stats) {
    int t = threadIdx.x;
    int d = t & 63;
    float ssum = 0.f, ssq = 0.f;
    for (int n = blockIdx.x * 4 + (t >> 6); n < NN; n += gridDim.x * 4) {
        float acc = cb[d];
        const float4* a4 = (const float4*)(agg + (size_t)n * DD);
#pragma unroll
        for (int k4 = 0; k4 < DD / 4; k4++) {
            float4 a = a4[k4];
            int k = k4 * 4;
            acc += a.x * cW[(k + 0) * DD + d] + a.y * cW[(k + 1) * DD + d] +
                   a.z * cW[(k + 2) * DD + d] + a.w * cW[(k + 3) * DD + d];
        }
        const float4* p4 = (const float4*)(pooled + (size_t)n * EF);
#pragma unroll
        for (int j4 = 0; j4 < EF / 4; j4++) {
            float4 p = p4[j4];
            int j = j4 * 4;
            acc += p.x * We[(j + 0) * DD + d] + p.y * We[(j + 1) * DD + d] +
                   p.z * We[(j + 2) * DD + d] + p.w * We[(j + 3) * DD + d];
        }
        float deg = (float)(row_ptr[n + 1] - row_ptr[n]);
        acc += deg * be[d];
        acc = fmaxf(acc, 0.f);
        x[(size_t)n * DD + d] = acc;
        ssum += acc;
        ssq += acc * acc;
    }
    __shared__ float sb[256], sq[256];
    sb[t] = ssum;
    sq[t] = ssq;
    __syncthreads();
    if (t < 64) {
        atomicAdd(&stats[t], sb[t] + sb[t + 64] + sb[t + 128] + sb[t + 192]);
        atomicAdd(&stats[64 + t], sq[t] + sq[t + 64] + sq[t + 128] + sq[t + 192]);
    }
}

// ---------------- y = relu(xb_norm@W + b + h); stats.  xb already normalized. ----------------
__global__ void kl2(const float* __restrict__ xb, const float* __restrict__ W,
                    const float* __restrict__ b, const float* __restrict__ h,
                    float* __restrict__ y, float* __restrict__ stats) {
    int t = threadIdx.x;
    int d = t & 63;
    float ssum = 0.f, ssq = 0.f;
    for (int n = blockIdx.x * 4 + (t >> 6); n < NN; n += gridDim.x * 4) {
        float acc = b[d];
        const float4* x4 = (const float4*)(xb + (size_t)n * DD);
#pragma unroll
        for (int k4 = 0; k4 < DD / 4; k4++) {
            float4 xv = x4[k4];
            int k = k4 * 4;
            acc += xv.x * W[(k + 0) * DD + d] + xv.y * W[(k + 1) * DD + d] +
                   xv.z * W[(k + 2) * DD + d] + xv.w * W[(k + 3) * DD + d];
        }
        acc += h[(size_t)n * DD + d];
        acc = fmaxf(acc, 0.f);
        y[(size_t)n * DD + d] = acc;
        ssum += acc;
        ssq += acc * acc;
    }
    __shared__ float sb[256], sq[256];
    sb[t] = ssum;
    sq[t] = ssq;
    __syncthreads();
    if (t < 64) {
        atomicAdd(&stats[t], sb[t] + sb[t + 64] + sb[t + 128] + sb[t + 192]);
        atomicAdd(&stats[64 + t], sq[t] + sq[t + 64] + sq[t + 128] + sq[t + 192]);
    }
}

// ---------------- segmented max readout (g_idx sorted) ----------------
__device__ __forceinline__ unsigned fenc(float f) {
    unsigned u = __float_as_uint(f);
    return (u >> 31) ? ~u : (u | 0x80000000u);
}
__device__ __forceinline__ float fdec(unsigned k) {
    return (k >> 31) ? __uint_as_float(k ^ 0x80000000u) : __uint_as_float(~k);
}

__global__ void kread(const float* __restrict__ h, const int* __restrict__ gidx,
                      unsigned* __restrict__ pk) {
    int lane = threadIdx.x & 63;
    int wid = threadIdx.x >> 6;
    int gw = blockIdx.x * 4 + wid;
    int nw = gridDim.x * 4;
    int chunk = (NN + nw - 1) / nw;
    int lo = gw * chunk, hi = min(lo + chunk, NN);
    if (lo >= hi) return;
    int cur = gidx[lo];
    float acc = -INFINITY;
    for (int n = lo; n < hi; n++) {
        int g = gidx[n];
        if (g != cur) {
            atomicMax(&pk[cur * DD + lane], fenc(acc));
            cur = g;
            acc = -INFINITY;
        }
        acc = fmaxf(acc, h[(size_t)n * DD + lane]);
    }
    atomicMax(&pk[cur * DD + lane], fenc(acc));
}

__global__ void kout(const unsigned* __restrict__ pk, const float* __restrict__ W,
                     const float* __restrict__ b, float* __restrict__ out) {
    int t = blockIdx.x * blockDim.x + threadIdx.x;  // GG*DD threads
    int g = t >> 6, d = t & 63;
    float acc = b[d];
    for (int k = 0; k < DD; k++) {
        float p = fdec(pk[g * DD + k]);
        acc += p * W[k * DD + d];
    }
    out[t] = fmaxf(acc, 0.f);
}

extern "C" void kernel_launch(void* const* d_in, const int* in_sizes, int n_in,
                              void* d_out, int out_size, void* d_ws, size_t ws_size,
                              hipStream_t stream) {
    const float* node_feat = (const float*)d_in[0];
    const float* edge_feat = (const float*)d_in[1];
    const float* w_n2l_W = (const float*)d_in[2];
    const float* w_n2l_b = (const float*)d_in[3];
    const float* nve = (const float*)d_in[4];
    const float* w_e2l_W = (const float*)d_in[5];
    const float* w_e2l_b = (const float*)d_in[6];
    const float* conv_W = (const float*)d_in[7];
    const float* conv_b = (const float*)d_in[8];
    const float* l2_W = (const float*)d_in[9];
    const float* l2_b = (const float*)d_in[10];
    const float* msg_g = (const float*)d_in[11];
    const float* msg_b = (const float*)d_in[12];
    const float* hid_g = (const float*)d_in[13];
    const float* hid_b = (const float*)d_in[14];
    const float* out_W = (const float*)d_in[15];
    const float* out_b = (const float*)d_in[16];
    const int* edge_from = (const int*)d_in[17];
    const int* edge_to = (const int*)d_in[18];
    const int* g_idx = (const int*)d_in[19];
    const int* nvi = (const int*)d_in[20];
    float* out = (float*)d_out;

    char* ws = (char*)d_ws;
    size_t off = 0;
    auto alloc = [&](size_t bytes) -> void* {
        void* p = ws + off;
        off += (bytes + 255) / 256 * 256;
        return p;
    };
    int* cnt = (int*)alloc((size_t)NN * 4);
    int* row_ptr = (int*)alloc((size_t)(NN + 1) * 4);
    int* cursor = (int*)alloc((size_t)NN * 4);
    int* eid = (int*)alloc((size_t)EE * 4);
    float* pooled_ef = (float*)alloc((size_t)NN * EF * 4);
    float* h = (float*)alloc((size_t)NN * DD * 4);
    float* xa = (float*)alloc((size_t)NN * DD * 4);
    float* xb = (float*)alloc((size_t)NN * DD * 4);
    float* stats = (float*)alloc(256 * 4);
    unsigned* pk = (unsigned*)alloc((size_t)GG * DD * 4);
    (void)ws_size;
    (void)n_in;
    (void)in_sizes;
    (void)out_size;

    hipMemsetAsync(cnt, 0, (size_t)NN * 4, stream);
    hipMemsetAsync(stats, 0, 256 * 4, stream);
    hipMemsetAsync(pk, 0, (size_t)GG * DD * 4, stream);

    const int NB = 2048, NT = 256;

    khist<<<(EE + 255) / 256, 256, 0, stream>>>(edge_to, cnt);
    kscan<<<1, 1024, 0, stream>>>(cnt, row_ptr, cursor);
    kreorder<<<(EE + 255) / 256, 256, 0, stream>>>(edge_to, cursor, eid);
    kpool<<<NB, NT, 0, stream>>>(edge_feat, row_ptr, eid, pooled_ef);

    kh0<<<NB, NT, 0, stream>>>(node_feat, w_n2l_W, w_n2l_b, nve, nvi, pooled_ef, row_ptr,
                               w_e2l_W, w_e2l_b, xa, stats);
    kfin<<<1, 64, 0, stream>>>(stats, msg_g, msg_b);
    knorm<<<NB, NT, 0, stream>>>(xa, stats, h);

    for (int lv = 0; lv < LVL; lv++) {
        kmsg<<<NB, NT, 0, stream>>>(h, row_ptr, eid, edge_from, xa);
        kmerge<<<NB, NT, 0, stream>>>(xa, conv_W + lv * DD * DD, conv_b + lv * DD, pooled_ef,
                                      w_e2l_W + (lv + 1) * EF * DD, w_e2l_b + (lv + 1) * DD,
                                      row_ptr, xb, stats);
        kfin<<<1, 64, 0, stream>>>(stats, hid_g + lv * DD, hid_b + lv * DD);
        knorm<<<NB, NT, 0, stream>>>(xb, stats, xb);
        kl2<<<NB, NT, 0, stream>>>(xb, l2_W + lv * DD * DD, l2_b + lv * DD, h, xa, stats);
        kfin<<<1, 64, 0, stream>>>(stats, msg_g + (lv + 1) * DD, msg_b + (lv + 1) * DD);
        knorm<<<NB, NT, 0, stream>>>(xa, stats, h);
    }

    kread<<<1024, 256, 0, stream>>>(h, g_idx, pk);
    kout<<<GG, DD, 0, stream>>>(pk, out_W, out_b, out);
}

// Round 2
// 1371.868 us; speedup vs baseline: 1.6272x; 1.6272x over previous
//
#include <hip/hip_runtime.h>
#include <math.h>

#define NN 100000
#define EE 1600000
#define GG 64
#define DD 64
#define NF 128
#define EF 32
#define LVL 3
#define EPSBN 1e-5f
#define NTILES ((NN + 63) / 64)

__device__ __forceinline__ float4 ld4(const float* p) { return *(const float4*)p; }

// ---------------- CSR build ----------------
__global__ void khist(const int* __restrict__ to, int* __restrict__ cnt) {
    int e = blockIdx.x * blockDim.x + threadIdx.x;
    if (e < EE) atomicAdd(&cnt[to[e]], 1);
}

__global__ void kscan(const int* __restrict__ cnt, int* __restrict__ row_ptr,
                      int* __restrict__ cursor) {
    __shared__ int part[1024];
    int t = threadIdx.x;
    const int C = (NN + 1023) / 1024;
    int lo = t * C, hi = min(lo + C, NN);
    int s = 0;
    for (int i = lo; i < hi; i++) s += cnt[i];
    part[t] = s;
    __syncthreads();
    for (int off = 1; off < 1024; off <<= 1) {
        int v = (t >= off) ? part[t - off] : 0;
        __syncthreads();
        part[t] += v;
        __syncthreads();
    }
    int run = (t == 0) ? 0 : part[t - 1];
    for (int i = lo; i < hi; i++) {
        row_ptr[i] = run;
        cursor[i] = run;
        run += cnt[i];
    }
    if (t == 0) row_ptr[NN] = part[1023];
}

__global__ void kreorder(const int* __restrict__ to, const int* __restrict__ from,
                         int* __restrict__ cursor, int* __restrict__ eid,
                         int* __restrict__ src) {
    int e = blockIdx.x * blockDim.x + threadIdx.x;
    if (e < EE) {
        int pos = atomicAdd(&cursor[to[e]], 1);
        eid[pos] = e;
        src[pos] = from[e];
    }
}

// ---------------- edge-feature pooling ----------------
__global__ void kpool(const float* __restrict__ ef, const int* __restrict__ row_ptr,
                      const int* __restrict__ eid, float* __restrict__ pooled) {
    int tid0 = blockIdx.x * blockDim.x + threadIdx.x;
    int stride = gridDim.x * blockDim.x;
    for (int tid = tid0; tid < NN * EF; tid += stride) {
        int n = tid >> 5, j = tid & 31;
        int e0 = row_ptr[n], e1 = row_ptr[n + 1];
        float s = 0.f;
        int e = e0;
        for (; e + 1 < e1; e += 2) {
            s += ef[(size_t)eid[e] * EF + j];
            s += ef[(size_t)eid[e + 1] * EF + j];
        }
        if (e < e1) s += ef[(size_t)eid[e] * EF + j];
        pooled[tid] = s;
    }
}

// ---------------- fused tiled GEMM + epilogue + BN stats ----------------
// C[n][ch] = relu( [A1|A2]@[W1;W2] + bias + deg*be + emb[nvi[n]] + resid*rsc+rsh )
// A1 optionally pre-scaled per-column by aaff (sc[64],sh[64]).
// Writes X raw (pre-BN) and accumulates per-channel sum/sumsq into stats[0..127].
__global__ void kgemm(const float* __restrict__ A1, int K1, int S1,
                      const float* __restrict__ A2, int K2,
                      const float* __restrict__ W1, const float* __restrict__ W2,
                      const float* __restrict__ bias, const float* __restrict__ be,
                      const int* __restrict__ row_ptr,
                      const float* __restrict__ emb, const int* __restrict__ nvi,
                      const float* __restrict__ resid, const float* __restrict__ raff,
                      const float* __restrict__ aaff,
                      float* __restrict__ X, float* __restrict__ stats) {
    extern __shared__ float smem[];
    const int K = K1 + K2;
    float* W_lds = smem;               // [K][64]
    float* A_lds = smem + K * 64;      // [64][36]
    float* red = A_lds + 64 * 36;      // [128]

    int t = threadIdx.x;
    int r = t >> 4;       // 0..15  (node sub-row)
    int c = t & 15;       // channels 4c..4c+3

    // stage W (k-major, no transpose)
    for (int idx = t; idx < K * 16; idx += 256) {
        int k = idx >> 4, ch4 = (idx & 15) * 4;
        float4 v = (k < K1) ? ld4(W1 + (size_t)k * 64 + ch4)
                            : ld4(W2 + (size_t)(k - K1) * 64 + ch4);
        *(float4*)&W_lds[k * 64 + ch4] = v;
    }

    float4 bias4 = ld4(bias + 4 * c);
    float4 be4 = make_float4(0, 0, 0, 0);
    if (be) be4 = ld4(be + 4 * c);
    float4 rsc4 = make_float4(0, 0, 0, 0), rsh4 = rsc4;
    if (resid) { rsc4 = ld4(raff + 4 * c); rsh4 = ld4(raff + 64 + 4 * c); }

    float4 ssum = make_float4(0, 0, 0, 0), ssq = make_float4(0, 0, 0, 0);

    int arow = t >> 2, aslot = t & 3;  // staging map: row 0..63, 8 cols each

    for (int tile = blockIdx.x; tile < NTILES; tile += gridDim.x) {
        int nb = tile * 64;
        float4 acc[4];
#pragma unroll
        for (int i = 0; i < 4; i++) acc[i] = make_float4(0, 0, 0, 0);

        for (int kk0 = 0; kk0 < K; kk0 += 32) {
            __syncthreads();
            // stage A chunk [64 rows][32 cols]
            {
                int node = nb + arow;
                int col = aslot * 8;
                float4 v0 = make_float4(0, 0, 0, 0), v1 = v0;
                if (node < NN) {
                    if (kk0 < K1) {
                        const float* p = A1 + (size_t)node * S1 + kk0 + col;
                        v0 = ld4(p);
                        v1 = ld4(p + 4);
                        if (aaff) {
                            float4 s0 = ld4(aaff + kk0 + col), s1 = ld4(aaff + kk0 + col + 4);
                            float4 h0 = ld4(aaff + 64 + kk0 + col), h1 = ld4(aaff + 64 + kk0 + col + 4);
                            v0.x = v0.x * s0.x + h0.x; v0.y = v0.y * s0.y + h0.y;
                            v0.z = v0.z * s0.z + h0.z; v0.w = v0.w * s0.w + h0.w;
                            v1.x = v1.x * s1.x + h1.x; v1.y = v1.y * s1.y + h1.y;
                            v1.z = v1.z * s1.z + h1.z; v1.w = v1.w * s1.w + h1.w;
                        }
                    } else {
                        const float* p = A2 + (size_t)node * K2 + (kk0 - K1) + col;
                        v0 = ld4(p);
                        v1 = ld4(p + 4);
                    }
                }
                *(float4*)&A_lds[arow * 36 + col] = v0;
                *(float4*)&A_lds[arow * 36 + col + 4] = v1;
            }
            __syncthreads();

            const float* wb = W_lds + (size_t)kk0 * 64 + 4 * c;
#pragma unroll
            for (int k4 = 0; k4 < 8; k4++) {
                float4 w0 = ld4(wb + (4 * k4 + 0) * 64);
                float4 w1 = ld4(wb + (4 * k4 + 1) * 64);
                float4 w2 = ld4(wb + (4 * k4 + 2) * 64);
                float4 w3 = ld4(wb + (4 * k4 + 3) * 64);
#pragma unroll
                for (int i = 0; i < 4; i++) {
                    float4 a = *(const float4*)&A_lds[(r + 16 * i) * 36 + 4 * k4];
                    acc[i].x += a.x * w0.x + a.y * w1.x + a.z * w2.x + a.w * w3.x;
                    acc[i].y += a.x * w0.y + a.y * w1.y + a.z * w2.y + a.w * w3.y;
                    acc[i].z += a.x * w0.z + a.y * w1.z + a.z * w2.z + a.w * w3.z;
                    acc[i].w += a.x * w0.w + a.y * w1.w + a.z * w2.w + a.w * w3.w;
                }
            }
        }

        // epilogue
#pragma unroll
        for (int i = 0; i < 4; i++) {
            int node = nb + r + 16 * i;
            if (node < NN) {
                float4 v = acc[i];
                v.x += bias4.x; v.y += bias4.y; v.z += bias4.z; v.w += bias4.w;
                if (be) {
                    float deg = (float)(row_ptr[node + 1] - row_ptr[node]);
                    v.x += deg * be4.x; v.y += deg * be4.y;
                    v.z += deg * be4.z; v.w += deg * be4.w;
                }
                if (emb) {
                    float4 e4 = ld4(emb + (size_t)nvi[node] * 64 + 4 * c);
                    v.x += e4.x; v.y += e4.y; v.z += e4.z; v.w += e4.w;
                }
                if (resid) {
                    float4 h4 = ld4(resid + (size_t)node * 64 + 4 * c);
                    v.x += h4.x * rsc4.x + rsh4.x; v.y += h4.y * rsc4.y + rsh4.y;
                    v.z += h4.z * rsc4.z + rsh4.z; v.w += h4.w * rsc4.w + rsh4.w;
                }
                v.x = fmaxf(v.x, 0.f); v.y = fmaxf(v.y, 0.f);
                v.z = fmaxf(v.z, 0.f); v.w = fmaxf(v.w, 0.f);
                *(float4*)&X[(size_t)node * 64 + 4 * c] = v;
                ssum.x += v.x; ssum.y += v.y; ssum.z += v.z; ssum.w += v.w;
                ssq.x += v.x * v.x; ssq.y += v.y * v.y;
                ssq.z += v.z * v.z; ssq.w += v.w * v.w;
            }
        }
    }

    // block-level stats reduce
    __syncthreads();
    if (t < 128) red[t] = 0.f;
    __syncthreads();
    atomicAdd(&red[4 * c + 0], ssum.x);
    atomicAdd(&red[4 * c + 1], ssum.y);
    atomicAdd(&red[4 * c + 2], ssum.z);
    atomicAdd(&red[4 * c + 3], ssum.w);
    atomicAdd(&red[64 + 4 * c + 0], ssq.x);
    atomicAdd(&red[64 + 4 * c + 1], ssq.y);
    atomicAdd(&red[64 + 4 * c + 2], ssq.z);
    atomicAdd(&red[64 + 4 * c + 3], ssq.w);
    __syncthreads();
    if (t < 128) atomicAdd(&stats[t], red[t]);
}

// ---------------- BN finalize: write affine slot, zero sums ----------------
__global__ void kfin(float* __restrict__ stats, const float* __restrict__ g,
                     const float* __restrict__ b, int slot) {
    int t = threadIdx.x;  // 64
    float mean = stats[t] * (1.0f / NN);
    float var = stats[64 + t] * (1.0f / NN) - mean * mean;
    float rstd = rsqrtf(fmaxf(var, 0.f) + EPSBN);
    float sc = g[t] * rstd;
    float* slotp = stats + 128 + slot * 128;
    slotp[t] = sc;
    slotp[64 + t] = b[t] - mean * sc;
    stats[t] = 0.f;
    stats[64 + t] = 0.f;
}

// ---------------- message passing: agg = sc*sum_e hraw[src] + deg*sh ----------------
__global__ void kmsg(const float* __restrict__ h, const int* __restrict__ row_ptr,
                     const int* __restrict__ src, const float* __restrict__ aff,
                     float* __restrict__ agg) {
    int lane = threadIdx.x & 63;
    int wid = threadIdx.x >> 6;
    float sc = aff[lane], sh = aff[64 + lane];
    for (int n = blockIdx.x * 4 + wid; n < NN; n += gridDim.x * 4) {
        int e0 = row_ptr[n], e1 = row_ptr[n + 1];
        float acc = 0.f;
        int e = e0;
        for (; e + 3 < e1; e += 4) {
            int s0 = src[e], s1 = src[e + 1], s2 = src[e + 2], s3 = src[e + 3];
            float v0 = h[(size_t)s0 * 64 + lane];
            float v1 = h[(size_t)s1 * 64 + lane];
            float v2 = h[(size_t)s2 * 64 + lane];
            float v3 = h[(size_t)s3 * 64 + lane];
            acc += (v0 + v1) + (v2 + v3);
        }
        for (; e < e1; ++e) acc += h[(size_t)src[e] * 64 + lane];
        agg[(size_t)n * 64 + lane] = sc * acc + (float)(e1 - e0) * sh;
    }
}

// ---------------- segmented max readout with affine ----------------
__device__ __forceinline__ unsigned fenc(float f) {
    unsigned u = __float_as_uint(f);
    return (u >> 31) ? ~u : (u | 0x80000000u);
}
__device__ __forceinline__ float fdec(unsigned k) {
    return (k >> 31) ? __uint_as_float(k ^ 0x80000000u) : __uint_as_float(~k);
}

__global__ void kinitpk(unsigned* __restrict__ pk) {
    int i = blockIdx.x * blockDim.x + threadIdx.x;
    if (i < GG * DD) pk[i] = 0x007FFFFFu;  // fenc(-inf)
}

__global__ void kread(const float* __restrict__ h, const int* __restrict__ gidx,
                      const float* __restrict__ aff, unsigned* __restrict__ pk) {
    int lane = threadIdx.x & 63;
    int wid = threadIdx.x >> 6;
    float sc = aff[lane], sh = aff[64 + lane];
    int gw = blockIdx.x * 4 + wid;
    int nw = gridDim.x * 4;
    int chunk = (NN + nw - 1) / nw;
    int lo = gw * chunk, hi = min(lo + chunk, NN);
    if (lo >= hi) return;
    int cur = gidx[lo];
    float acc = -INFINITY;
    for (int n = lo; n < hi; n++) {
        int g = gidx[n];
        if (g != cur) {
            atomicMax(&pk[cur * DD + lane], fenc(acc));
            cur = g;
            acc = -INFINITY;
        }
        acc = fmaxf(acc, h[(size_t)n * 64 + lane] * sc + sh);
    }
    atomicMax(&pk[cur * DD + lane], fenc(acc));
}

__global__ void kout(const unsigned* __restrict__ pk, const float* __restrict__ W,
                     const float* __restrict__ b, float* __restrict__ out) {
    int t = blockIdx.x * blockDim.x + threadIdx.x;
    int g = t >> 6, d = t & 63;
    float acc = b[d];
    for (int k = 0; k < DD; k++) {
        float p = fdec(pk[g * DD + k]);
        acc += p * W[k * DD + d];
    }
    out[t] = fmaxf(acc, 0.f);
}

extern "C" void kernel_launch(void* const* d_in, const int* in_sizes, int n_in,
                              void* d_out, int out_size, void* d_ws, size_t ws_size,
                              hipStream_t stream) {
    const float* node_feat = (const float*)d_in[0];
    const float* edge_feat = (const float*)d_in[1];
    const float* w_n2l_W = (const float*)d_in[2];
    const float* w_n2l_b = (const float*)d_in[3];
    const float* nve = (const float*)d_in[4];
    const float* w_e2l_W = (const float*)d_in[5];
    const float* w_e2l_b = (const float*)d_in[6];
    const float* conv_W = (const float*)d_in[7];
    const float* conv_b = (const float*)d_in[8];
    const float* l2_W = (const float*)d_in[9];
    const float* l2_b = (const float*)d_in[10];
    const float* msg_g = (const float*)d_in[11];
    const float* msg_b = (const float*)d_in[12];
    const float* hid_g = (const float*)d_in[13];
    const float* hid_b = (const float*)d_in[14];
    const float* out_W = (const float*)d_in[15];
    const float* out_b = (const float*)d_in[16];
    const int* edge_from = (const int*)d_in[17];
    const int* edge_to = (const int*)d_in[18];
    const int* g_idx = (const int*)d_in[19];
    const int* nvi = (const int*)d_in[20];
    float* out = (float*)d_out;

    char* ws = (char*)d_ws;
    size_t off = 0;
    auto alloc = [&](size_t bytes) -> void* {
        void* p = ws + off;
        off += (bytes + 255) / 256 * 256;
        return p;
    };
    int* cnt = (int*)alloc((size_t)NN * 4);
    int* row_ptr = (int*)alloc((size_t)(NN + 1) * 4);
    int* cursor = (int*)alloc((size_t)NN * 4);
    int* eid = (int*)alloc((size_t)EE * 4);
    int* srcarr = (int*)alloc((size_t)EE * 4);
    float* pooled_ef = (float*)alloc((size_t)NN * EF * 4);
    float* hb0 = (float*)alloc((size_t)NN * DD * 4);
    float* hb1 = (float*)alloc((size_t)NN * DD * 4);
    float* aggb = (float*)alloc((size_t)NN * DD * 4);
    float* mb = (float*)alloc((size_t)NN * DD * 4);
    float* stats = (float*)alloc(1024 * 4);
    unsigned* pk = (unsigned*)alloc((size_t)GG * DD * 4);
    (void)ws_size; (void)n_in; (void)in_sizes; (void)out_size;

    hipMemsetAsync(cnt, 0, (size_t)NN * 4, stream);
    hipMemsetAsync(stats, 0, 1024 * 4, stream);
    kinitpk<<<16, 256, 0, stream>>>(pk);

    khist<<<(EE + 255) / 256, 256, 0, stream>>>(edge_to, cnt);
    kscan<<<1, 1024, 0, stream>>>(cnt, row_ptr, cursor);
    kreorder<<<(EE + 255) / 256, 256, 0, stream>>>(edge_to, edge_from, cursor, eid, srcarr);
    kpool<<<2048, 256, 0, stream>>>(edge_feat, row_ptr, eid, pooled_ef);

    const int GB = 782;
    auto smem_for = [](int K) { return (size_t)(K * 64 + 64 * 36 + 128) * 4; };

    // h0 = relu(node_feat@W + b + emb + pooled@We0 + deg*be0)
    kgemm<<<GB, 256, smem_for(NF + EF), stream>>>(
        node_feat, NF, NF, pooled_ef, EF, w_n2l_W, w_e2l_W, w_n2l_b, w_e2l_b,
        row_ptr, nve, nvi, nullptr, nullptr, nullptr, hb0, stats);
    kfin<<<1, 64, 0, stream>>>(stats, msg_g, msg_b, 0);

    float* hcur = hb0;
    float* hnext = hb1;
    for (int lv = 0; lv < LVL; lv++) {
        kmsg<<<2048, 256, 0, stream>>>(hcur, row_ptr, srcarr, stats + 128 + lv * 128, aggb);
        // merged_raw = relu(agg@cW + cb + pooled@We + deg*be)
        kgemm<<<GB, 256, smem_for(DD + EF), stream>>>(
            aggb, DD, DD, pooled_ef, EF, conv_W + lv * DD * DD,
            w_e2l_W + (size_t)(lv + 1) * EF * DD, conv_b + lv * DD,
            w_e2l_b + (size_t)(lv + 1) * DD, row_ptr, nullptr, nullptr,
            nullptr, nullptr, nullptr, mb, stats);
        kfin<<<1, 64, 0, stream>>>(stats, hid_g + lv * DD, hid_b + lv * DD, 4 + lv);
        // hnext = relu(bn(merged)@l2W + l2b + bn(hcur))
        kgemm<<<GB, 256, smem_for(DD), stream>>>(
            mb, DD, DD, nullptr, 0, l2_W + lv * DD * DD, nullptr, l2_b + lv * DD,
            nullptr, nullptr, nullptr, nullptr, hcur, stats + 128 + lv * 128,
            stats + 128 + (4 + lv) * 128, hnext, stats);
        kfin<<<1, 64, 0, stream>>>(stats, msg_g + (lv + 1) * DD, msg_b + (lv + 1) * DD, lv + 1);
        float* tmp = hcur; hcur = hnext; hnext = tmp;
    }

    kread<<<1024, 256, 0, stream>>>(hcur, g_idx, stats + 128 + LVL * 128, pk);
    kout<<<GG, 64, 0, stream>>>(pk, out_W, out_b, out);
}

// Round 3
// 1152.510 us; speedup vs baseline: 1.9369x; 1.1903x over previous
//
#include <hip/hip_runtime.h>
#include <math.h>

#define NN 100000
#define EE 1600000
#define GG 64
#define DD 64
#define NF 128
#define EF 32
#define LVL 3
#define EPSBN 1e-5f
#define NTILES ((NN + 63) / 64)
#define NBS ((NN + 255) / 256)   // 391 scan blocks

__device__ __forceinline__ float4 ld4(const float* p) { return *(const float4*)p; }

// ---------------- CSR build ----------------
__global__ void khist(const int* __restrict__ to, int* __restrict__ cnt) {
    int e = blockIdx.x * blockDim.x + threadIdx.x;
    if (e < EE) atomicAdd(&cnt[to[e]], 1);
}

// phase 1: per-block sums of cnt
__global__ void kbsum(const int* __restrict__ cnt, int* __restrict__ bsum) {
    __shared__ int s[256];
    int t = threadIdx.x;
    int i = blockIdx.x * 256 + t;
    s[t] = (i < NN) ? cnt[i] : 0;
    __syncthreads();
    for (int off = 128; off > 0; off >>= 1) {
        if (t < off) s[t] += s[t + off];
        __syncthreads();
    }
    if (t == 0) bsum[blockIdx.x] = s[0];
}

// phase 2: single small block scans the 391 block sums -> exclusive offsets
__global__ void kbscan(const int* __restrict__ bsum, int* __restrict__ boff) {
    __shared__ int s[512];
    int t = threadIdx.x;
    s[t] = (t < NBS) ? bsum[t] : 0;
    __syncthreads();
    for (int off = 1; off < 512; off <<= 1) {
        int v = (t >= off) ? s[t - off] : 0;
        __syncthreads();
        s[t] += v;
        __syncthreads();
    }
    if (t < NBS) boff[t] = (t == 0) ? 0 : s[t - 1];
}

// phase 3: in-block scan + offset -> row_ptr, cursor
__global__ void kfscan(const int* __restrict__ cnt, const int* __restrict__ boff,
                       int* __restrict__ row_ptr, int* __restrict__ cursor) {
    __shared__ int s[256];
    int t = threadIdx.x;
    int b = blockIdx.x;
    int i = b * 256 + t;
    int v = (i < NN) ? cnt[i] : 0;
    s[t] = v;
    __syncthreads();
    for (int off = 1; off < 256; off <<= 1) {
        int u = (t >= off) ? s[t - off] : 0;
        __syncthreads();
        s[t] += u;
        __syncthreads();
    }
    if (i < NN) {
        int excl = boff[b] + s[t] - v;
        row_ptr[i] = excl;
        cursor[i] = excl;
        if (i == NN - 1) row_ptr[NN] = boff[b] + s[t];
    }
}

__global__ void kreorder(const int* __restrict__ to, const int* __restrict__ from,
                         int* __restrict__ cursor, int* __restrict__ eid,
                         int* __restrict__ src) {
    int e = blockIdx.x * blockDim.x + threadIdx.x;
    if (e < EE) {
        int pos = atomicAdd(&cursor[to[e]], 1);
        eid[pos] = e;
        src[pos] = from[e];
    }
}

// ---------------- edge-feature pooling ----------------
__global__ void kpool(const float* __restrict__ ef, const int* __restrict__ row_ptr,
                      const int* __restrict__ eid, float* __restrict__ pooled) {
    int tid0 = blockIdx.x * blockDim.x + threadIdx.x;
    int stride = gridDim.x * blockDim.x;
    for (int tid = tid0; tid < NN * EF; tid += stride) {
        int n = tid >> 5, j = tid & 31;
        int e0 = row_ptr[n], e1 = row_ptr[n + 1];
        float s = 0.f;
        int e = e0;
        for (; e + 1 < e1; e += 2) {
            s += ef[(size_t)eid[e] * EF + j];
            s += ef[(size_t)eid[e + 1] * EF + j];
        }
        if (e < e1) s += ef[(size_t)eid[e] * EF + j];
        pooled[tid] = s;
    }
}

// ---------------- fused tiled GEMM + epilogue + BN stats ----------------
__global__ void kgemm(const float* __restrict__ A1, int K1, int S1,
                      const float* __restrict__ A2, int K2,
                      const float* __restrict__ W1, const float* __restrict__ W2,
                      const float* __restrict__ bias, const float* __restrict__ be,
                      const int* __restrict__ row_ptr,
                      const float* __restrict__ emb, const int* __restrict__ nvi,
                      const float* __restrict__ resid, const float* __restrict__ raff,
                      const float* __restrict__ aaff,
                      float* __restrict__ X, float* __restrict__ stats) {
    extern __shared__ float smem[];
    const int K = K1 + K2;
    float* W_lds = smem;               // [K][64]
    float* A_lds = smem + K * 64;      // [64][36]
    float* red = A_lds + 64 * 36;      // [128]

    int t = threadIdx.x;
    int r = t >> 4;       // 0..15  (node sub-row)
    int c = t & 15;       // channels 4c..4c+3

    for (int idx = t; idx < K * 16; idx += 256) {
        int k = idx >> 4, ch4 = (idx & 15) * 4;
        float4 v = (k < K1) ? ld4(W1 + (size_t)k * 64 + ch4)
                            : ld4(W2 + (size_t)(k - K1) * 64 + ch4);
        *(float4*)&W_lds[k * 64 + ch4] = v;
    }

    float4 bias4 = ld4(bias + 4 * c);
    float4 be4 = make_float4(0, 0, 0, 0);
    if (be) be4 = ld4(be + 4 * c);
    float4 rsc4 = make_float4(0, 0, 0, 0), rsh4 = rsc4;
    if (resid) { rsc4 = ld4(raff + 4 * c); rsh4 = ld4(raff + 64 + 4 * c); }

    float4 ssum = make_float4(0, 0, 0, 0), ssq = make_float4(0, 0, 0, 0);

    int arow = t >> 2, aslot = t & 3;

    for (int tile = blockIdx.x; tile < NTILES; tile += gridDim.x) {
        int nb = tile * 64;
        float4 acc[4];
#pragma unroll
        for (int i = 0; i < 4; i++) acc[i] = make_float4(0, 0, 0, 0);

        for (int kk0 = 0; kk0 < K; kk0 += 32) {
            __syncthreads();
            {
                int node = nb + arow;
                int col = aslot * 8;
                float4 v0 = make_float4(0, 0, 0, 0), v1 = v0;
                if (node < NN) {
                    if (kk0 < K1) {
                        const float* p = A1 + (size_t)node * S1 + kk0 + col;
                        v0 = ld4(p);
                        v1 = ld4(p + 4);
                        if (aaff) {
                            float4 s0 = ld4(aaff + kk0 + col), s1 = ld4(aaff + kk0 + col + 4);
                            float4 h0 = ld4(aaff + 64 + kk0 + col), h1 = ld4(aaff + 64 + kk0 + col + 4);
                            v0.x = v0.x * s0.x + h0.x; v0.y = v0.y * s0.y + h0.y;
                            v0.z = v0.z * s0.z + h0.z; v0.w = v0.w * s0.w + h0.w;
                            v1.x = v1.x * s1.x + h1.x; v1.y = v1.y * s1.y + h1.y;
                            v1.z = v1.z * s1.z + h1.z; v1.w = v1.w * s1.w + h1.w;
                        }
                    } else {
                        const float* p = A2 + (size_t)node * K2 + (kk0 - K1) + col;
                        v0 = ld4(p);
                        v1 = ld4(p + 4);
                    }
                }
                *(float4*)&A_lds[arow * 36 + col] = v0;
                *(float4*)&A_lds[arow * 36 + col + 4] = v1;
            }
            __syncthreads();

            const float* wb = W_lds + (size_t)kk0 * 64 + 4 * c;
#pragma unroll
            for (int k4 = 0; k4 < 8; k4++) {
                float4 w0 = ld4(wb + (4 * k4 + 0) * 64);
                float4 w1 = ld4(wb + (4 * k4 + 1) * 64);
                float4 w2 = ld4(wb + (4 * k4 + 2) * 64);
                float4 w3 = ld4(wb + (4 * k4 + 3) * 64);
#pragma unroll
                for (int i = 0; i < 4; i++) {
                    float4 a = *(const float4*)&A_lds[(r + 16 * i) * 36 + 4 * k4];
                    acc[i].x += a.x * w0.x + a.y * w1.x + a.z * w2.x + a.w * w3.x;
                    acc[i].y += a.x * w0.y + a.y * w1.y + a.z * w2.y + a.w * w3.y;
                    acc[i].z += a.x * w0.z + a.y * w1.z + a.z * w2.z + a.w * w3.z;
                    acc[i].w += a.x * w0.w + a.y * w1.w + a.z * w2.w + a.w * w3.w;
                }
            }
        }

#pragma unroll
        for (int i = 0; i < 4; i++) {
            int node = nb + r + 16 * i;
            if (node < NN) {
                float4 v = acc[i];
                v.x += bias4.x; v.y += bias4.y; v.z += bias4.z; v.w += bias4.w;
                if (be) {
                    float deg = (float)(row_ptr[node + 1] - row_ptr[node]);
                    v.x += deg * be4.x; v.y += deg * be4.y;
                    v.z += deg * be4.z; v.w += deg * be4.w;
                }
                if (emb) {
                    float4 e4 = ld4(emb + (size_t)nvi[node] * 64 + 4 * c);
                    v.x += e4.x; v.y += e4.y; v.z += e4.z; v.w += e4.w;
                }
                if (resid) {
                    float4 h4 = ld4(resid + (size_t)node * 64 + 4 * c);
                    v.x += h4.x * rsc4.x + rsh4.x; v.y += h4.y * rsc4.y + rsh4.y;
                    v.z += h4.z * rsc4.z + rsh4.z; v.w += h4.w * rsc4.w + rsh4.w;
                }
                v.x = fmaxf(v.x, 0.f); v.y = fmaxf(v.y, 0.f);
                v.z = fmaxf(v.z, 0.f); v.w = fmaxf(v.w, 0.f);
                *(float4*)&X[(size_t)node * 64 + 4 * c] = v;
                ssum.x += v.x; ssum.y += v.y; ssum.z += v.z; ssum.w += v.w;
                ssq.x += v.x * v.x; ssq.y += v.y * v.y;
                ssq.z += v.z * v.z; ssq.w += v.w * v.w;
            }
        }
    }

    __syncthreads();
    if (t < 128) red[t] = 0.f;
    __syncthreads();
    atomicAdd(&red[4 * c + 0], ssum.x);
    atomicAdd(&red[4 * c + 1], ssum.y);
    atomicAdd(&red[4 * c + 2], ssum.z);
    atomicAdd(&red[4 * c + 3], ssum.w);
    atomicAdd(&red[64 + 4 * c + 0], ssq.x);
    atomicAdd(&red[64 + 4 * c + 1], ssq.y);
    atomicAdd(&red[64 + 4 * c + 2], ssq.z);
    atomicAdd(&red[64 + 4 * c + 3], ssq.w);
    __syncthreads();
    if (t < 128) atomicAdd(&stats[t], red[t]);
}

// ---------------- BN finalize ----------------
__global__ void kfin(float* __restrict__ stats, const float* __restrict__ g,
                     const float* __restrict__ b, int slot) {
    int t = threadIdx.x;  // 64
    float mean = stats[t] * (1.0f / NN);
    float var = stats[64 + t] * (1.0f / NN) - mean * mean;
    float rstd = rsqrtf(fmaxf(var, 0.f) + EPSBN);
    float sc = g[t] * rstd;
    float* slotp = stats + 128 + slot * 128;
    slotp[t] = sc;
    slotp[64 + t] = b[t] - mean * sc;
    stats[t] = 0.f;
    stats[64 + t] = 0.f;
}

// ---------------- message passing ----------------
__global__ void kmsg(const float* __restrict__ h, const int* __restrict__ row_ptr,
                     const int* __restrict__ src, const float* __restrict__ aff,
                     float* __restrict__ agg) {
    int lane = threadIdx.x & 63;
    int wid = threadIdx.x >> 6;
    float sc = aff[lane], sh = aff[64 + lane];
    for (int n = blockIdx.x * 4 + wid; n < NN; n += gridDim.x * 4) {
        int e0 = row_ptr[n], e1 = row_ptr[n + 1];
        float acc = 0.f;
        int e = e0;
        for (; e + 3 < e1; e += 4) {
            int s0 = src[e], s1 = src[e + 1], s2 = src[e + 2], s3 = src[e + 3];
            float v0 = h[(size_t)s0 * 64 + lane];
            float v1 = h[(size_t)s1 * 64 + lane];
            float v2 = h[(size_t)s2 * 64 + lane];
            float v3 = h[(size_t)s3 * 64 + lane];
            acc += (v0 + v1) + (v2 + v3);
        }
        for (; e < e1; ++e) acc += h[(size_t)src[e] * 64 + lane];
        agg[(size_t)n * 64 + lane] = sc * acc + (float)(e1 - e0) * sh;
    }
}

// ---------------- segmented max readout ----------------
__device__ __forceinline__ unsigned fenc(float f) {
    unsigned u = __float_as_uint(f);
    return (u >> 31) ? ~u : (u | 0x80000000u);
}
__device__ __forceinline__ float fdec(unsigned k) {
    return (k >> 31) ? __uint_as_float(k ^ 0x80000000u) : __uint_as_float(~k);
}

__global__ void kinitpk(unsigned* __restrict__ pk) {
    int i = blockIdx.x * blockDim.x + threadIdx.x;
    if (i < GG * DD) pk[i] = 0x007FFFFFu;  // fenc(-inf)
}

__global__ void kread(const float* __restrict__ h, const int* __restrict__ gidx,
                      const float* __restrict__ aff, unsigned* __restrict__ pk) {
    int lane = threadIdx.x & 63;
    int wid = threadIdx.x >> 6;
    float sc = aff[lane], sh = aff[64 + lane];
    int gw = blockIdx.x * 4 + wid;
    int nw = gridDim.x * 4;
    int chunk = (NN + nw - 1) / nw;
    int lo = gw * chunk, hi = min(lo + chunk, NN);
    if (lo >= hi) return;
    int cur = gidx[lo];
    float acc = -INFINITY;
    for (int n = lo; n < hi; n++) {
        int g = gidx[n];
        if (g != cur) {
            atomicMax(&pk[cur * DD + lane], fenc(acc));
            cur = g;
            acc = -INFINITY;
        }
        acc = fmaxf(acc, h[(size_t)n * 64 + lane] * sc + sh);
    }
    atomicMax(&pk[cur * DD + lane], fenc(acc));
}

__global__ void kout(const unsigned* __restrict__ pk, const float* __restrict__ W,
                     const float* __restrict__ b, float* __restrict__ out) {
    int t = blockIdx.x * blockDim.x + threadIdx.x;
    int g = t >> 6, d = t & 63;
    float acc = b[d];
    for (int k = 0; k < DD; k++) {
        float p = fdec(pk[g * DD + k]);
        acc += p * W[k * DD + d];
    }
    out[t] = fmaxf(acc, 0.f);
}

extern "C" void kernel_launch(void* const* d_in, const int* in_sizes, int n_in,
                              void* d_out, int out_size, void* d_ws, size_t ws_size,
                              hipStream_t stream) {
    const float* node_feat = (const float*)d_in[0];
    const float* edge_feat = (const float*)d_in[1];
    const float* w_n2l_W = (const float*)d_in[2];
    const float* w_n2l_b = (const float*)d_in[3];
    const float* nve = (const float*)d_in[4];
    const float* w_e2l_W = (const float*)d_in[5];
    const float* w_e2l_b = (const float*)d_in[6];
    const float* conv_W = (const float*)d_in[7];
    const float* conv_b = (const float*)d_in[8];
    const float* l2_W = (const float*)d_in[9];
    const float* l2_b = (const float*)d_in[10];
    const float* msg_g = (const float*)d_in[11];
    const float* msg_b = (const float*)d_in[12];
    const float* hid_g = (const float*)d_in[13];
    const float* hid_b = (const float*)d_in[14];
    const float* out_W = (const float*)d_in[15];
    const float* out_b = (const float*)d_in[16];
    const int* edge_from = (const int*)d_in[17];
    const int* edge_to = (const int*)d_in[18];
    const int* g_idx = (const int*)d_in[19];
    const int* nvi = (const int*)d_in[20];
    float* out = (float*)d_out;

    char* ws = (char*)d_ws;
    size_t off = 0;
    auto alloc = [&](size_t bytes) -> void* {
        void* p = ws + off;
        off += (bytes + 255) / 256 * 256;
        return p;
    };
    int* cnt = (int*)alloc((size_t)NN * 4);
    int* row_ptr = (int*)alloc((size_t)(NN + 1) * 4);
    int* cursor = (int*)alloc((size_t)NN * 4);
    int* eid = (int*)alloc((size_t)EE * 4);
    int* srcarr = (int*)alloc((size_t)EE * 4);
    float* pooled_ef = (float*)alloc((size_t)NN * EF * 4);
    float* hb0 = (float*)alloc((size_t)NN * DD * 4);
    float* hb1 = (float*)alloc((size_t)NN * DD * 4);
    float* aggb = (float*)alloc((size_t)NN * DD * 4);
    float* mb = (float*)alloc((size_t)NN * DD * 4);
    float* stats = (float*)alloc(1024 * 4);
    unsigned* pk = (unsigned*)alloc((size_t)GG * DD * 4);
    int* bsum = (int*)alloc((size_t)NBS * 4);
    int* boff = (int*)alloc((size_t)512 * 4);
    (void)ws_size; (void)n_in; (void)in_sizes; (void)out_size;

    hipMemsetAsync(cnt, 0, (size_t)NN * 4, stream);
    hipMemsetAsync(stats, 0, 1024 * 4, stream);
    kinitpk<<<16, 256, 0, stream>>>(pk);

    khist<<<(EE + 255) / 256, 256, 0, stream>>>(edge_to, cnt);
    kbsum<<<NBS, 256, 0, stream>>>(cnt, bsum);
    kbscan<<<1, 512, 0, stream>>>(bsum, boff);
    kfscan<<<NBS, 256, 0, stream>>>(cnt, boff, row_ptr, cursor);
    kreorder<<<(EE + 255) / 256, 256, 0, stream>>>(edge_to, edge_from, cursor, eid, srcarr);
    kpool<<<2048, 256, 0, stream>>>(edge_feat, row_ptr, eid, pooled_ef);

    const int GB = 782;
    auto smem_for = [](int K) { return (size_t)(K * 64 + 64 * 36 + 128) * 4; };

    kgemm<<<GB, 256, smem_for(NF + EF), stream>>>(
        node_feat, NF, NF, pooled_ef, EF, w_n2l_W, w_e2l_W, w_n2l_b, w_e2l_b,
        row_ptr, nve, nvi, nullptr, nullptr, nullptr, hb0, stats);
    kfin<<<1, 64, 0, stream>>>(stats, msg_g, msg_b, 0);

    float* hcur = hb0;
    float* hnext = hb1;
    for (int lv = 0; lv < LVL; lv++) {
        kmsg<<<2048, 256, 0, stream>>>(hcur, row_ptr, srcarr, stats + 128 + lv * 128, aggb);
        kgemm<<<GB, 256, smem_for(DD + EF), stream>>>(
            aggb, DD, DD, pooled_ef, EF, conv_W + lv * DD * DD,
            w_e2l_W + (size_t)(lv + 1) * EF * DD, conv_b + lv * DD,
            w_e2l_b + (size_t)(lv + 1) * DD, row_ptr, nullptr, nullptr,
            nullptr, nullptr, nullptr, mb, stats);
        kfin<<<1, 64, 0, stream>>>(stats, hid_g + lv * DD, hid_b + lv * DD, 4 + lv);
        kgemm<<<GB, 256, smem_for(DD), stream>>>(
            mb, DD, DD, nullptr, 0, l2_W + lv * DD * DD, nullptr, l2_b + lv * DD,
            nullptr, nullptr, nullptr, nullptr, hcur, stats + 128 + lv * 128,
            stats + 128 + (4 + lv) * 128, hnext, stats);
        kfin<<<1, 64, 0, stream>>>(stats, msg_g + (lv + 1) * DD, msg_b + (lv + 1) * DD, lv + 1);
        float* tmp = hcur; hcur = hnext; hnext = tmp;
    }

    kread<<<1024, 256, 0, stream>>>(hcur, g_idx, stats + 128 + LVL * 128, pk);
    kout<<<GG, 64, 0, stream>>>(pk, out_W, out_b, out);
}

// Round 4
// 822.259 us; speedup vs baseline: 2.7148x; 1.4016x over previous
//
#include <hip/hip_runtime.h>
#include <math.h>

#define NN 100000
#define EE 1600000
#define GG 64
#define DD 64
#define NF 128
#define EF 32
#define LVL 3
#define EPSBN 1e-5f
#define NTILES ((NN + 63) / 64)
#define NBS ((NN + 255) / 256)

typedef unsigned short u16;
typedef unsigned int u32;
typedef short s4v __attribute__((ext_vector_type(4)));
typedef short bf16x8 __attribute__((ext_vector_type(8)));
typedef float f32x4 __attribute__((ext_vector_type(4)));

__device__ __forceinline__ float4 ld4(const float* p) { return *(const float4*)p; }
__device__ __forceinline__ u16 f2b(float f) {
    u32 u = __float_as_uint(f);
    return (u16)((u + 0x7FFFu + ((u >> 16) & 1u)) >> 16);
}
__device__ __forceinline__ float b2f(u16 u) { return __uint_as_float(((u32)u) << 16); }
__device__ __forceinline__ float blo(u32 u) { return __uint_as_float(u << 16); }
__device__ __forceinline__ float bhi(u32 u) { return __uint_as_float(u & 0xFFFF0000u); }

// ---------------- CSR build ----------------
__global__ void khist(const int* __restrict__ to, int* __restrict__ cnt) {
    int e = blockIdx.x * blockDim.x + threadIdx.x;
    if (e < EE) atomicAdd(&cnt[to[e]], 1);
}

__global__ void kbsum(const int* __restrict__ cnt, int* __restrict__ bsum) {
    __shared__ int s[256];
    int t = threadIdx.x;
    int i = blockIdx.x * 256 + t;
    s[t] = (i < NN) ? cnt[i] : 0;
    __syncthreads();
    for (int off = 128; off > 0; off >>= 1) {
        if (t < off) s[t] += s[t + off];
        __syncthreads();
    }
    if (t == 0) bsum[blockIdx.x] = s[0];
}

__global__ void kbscan(const int* __restrict__ bsum, int* __restrict__ boff) {
    __shared__ int s[512];
    int t = threadIdx.x;
    s[t] = (t < NBS) ? bsum[t] : 0;
    __syncthreads();
    for (int off = 1; off < 512; off <<= 1) {
        int v = (t >= off) ? s[t - off] : 0;
        __syncthreads();
        s[t] += v;
        __syncthreads();
    }
    if (t < NBS) boff[t] = (t == 0) ? 0 : s[t - 1];
}

__global__ void kfscan(const int* __restrict__ cnt, const int* __restrict__ boff,
                       int* __restrict__ row_ptr, int* __restrict__ cursor) {
    __shared__ int s[256];
    int t = threadIdx.x;
    int b = blockIdx.x;
    int i = b * 256 + t;
    int v = (i < NN) ? cnt[i] : 0;
    s[t] = v;
    __syncthreads();
    for (int off = 1; off < 256; off <<= 1) {
        int u = (t >= off) ? s[t - off] : 0;
        __syncthreads();
        s[t] += u;
        __syncthreads();
    }
    if (i < NN) {
        int excl = boff[b] + s[t] - v;
        row_ptr[i] = excl;
        cursor[i] = excl;
        if (i == NN - 1) row_ptr[NN] = boff[b] + s[t];
    }
}

__global__ void kreorder(const int* __restrict__ to, const int* __restrict__ from,
                         int* __restrict__ cursor, int* __restrict__ eid,
                         int* __restrict__ src) {
    int e = blockIdx.x * blockDim.x + threadIdx.x;
    if (e < EE) {
        int pos = atomicAdd(&cursor[to[e]], 1);
        eid[pos] = e;
        src[pos] = from[e];
    }
}

// ---------------- edge-feature pooling (fp32) ----------------
__global__ void kpool(const float* __restrict__ ef, const int* __restrict__ row_ptr,
                      const int* __restrict__ eid, float* __restrict__ pooled) {
    int tid0 = blockIdx.x * blockDim.x + threadIdx.x;
    int stride = gridDim.x * blockDim.x;
    for (int tid = tid0; tid < NN * EF; tid += stride) {
        int n = tid >> 5, j = tid & 31;
        int e0 = row_ptr[n], e1 = row_ptr[n + 1];
        float s = 0.f;
        int e = e0;
        for (; e + 1 < e1; e += 2) {
            s += ef[(size_t)eid[e] * EF + j];
            s += ef[(size_t)eid[e + 1] * EF + j];
        }
        if (e < e1) s += ef[(size_t)eid[e] * EF + j];
        pooled[tid] = s;
    }
}

// ---------------- MFMA bf16 fused GEMM ----------------
// out[n][ch] = relu( [A1|A2] @ [W1;W2] + bias + deg*be + emb[nvi] + resid*rsc+rsh )
// A1 fp32 or bf16 (optionally per-k affine aaff), A2 fp32. Weights fp32 -> bf16.
// Writes optional fp32 Xf and packed-bf16 Xb; accumulates BN stats.
template <int K1, int K2, bool A1BF, bool AAFF, bool EMB, bool BE, bool RESID,
          bool OUTF, bool OUTB>
__global__ __launch_bounds__(256) void kgemm_mfma(
    const void* __restrict__ A1v, const float* __restrict__ A2,
    const float* __restrict__ W1, const float* __restrict__ W2,
    const float* __restrict__ bias, const float* __restrict__ be,
    const int* __restrict__ row_ptr, const float* __restrict__ emb,
    const int* __restrict__ nvi, const float* __restrict__ resid,
    const float* __restrict__ raff, const float* __restrict__ aaff,
    float* __restrict__ Xf, u16* __restrict__ Xb, float* __restrict__ stats) {
    constexpr int K = K1 + K2;
    constexpr int KP = K + 8;
    __shared__ u16 A_lds[64 * KP];
    __shared__ u16 Wt_lds[64 * KP];
    __shared__ float red[128];

    const int t = threadIdx.x;
    const int lane = t & 63;
    const int wv = t >> 6;
    const int l15 = lane & 15;
    const int lg = lane >> 4;

    // stage W^T (bf16) once per block
    for (int idx = t; idx < K * 16; idx += 256) {
        int k = idx >> 4, c4 = (idx & 15) * 4;
        float4 w4 = (k < K1) ? ld4(W1 + (size_t)k * 64 + c4)
                             : ld4(W2 + (size_t)(k - K1) * 64 + c4);
        Wt_lds[(c4 + 0) * KP + k] = f2b(w4.x);
        Wt_lds[(c4 + 1) * KP + k] = f2b(w4.y);
        Wt_lds[(c4 + 2) * KP + k] = f2b(w4.z);
        Wt_lds[(c4 + 3) * KP + k] = f2b(w4.w);
    }
    if (t < 128) red[t] = 0.f;

    float bias_c[4], be_c[4], rsc_c[4], rsh_c[4];
#pragma unroll
    for (int n = 0; n < 4; n++) {
        int ch = 16 * n + l15;
        bias_c[n] = bias[ch];
        be_c[n] = BE ? be[ch] : 0.f;
        rsc_c[n] = RESID ? raff[ch] : 0.f;
        rsh_c[n] = RESID ? raff[64 + ch] : 0.f;
    }

    for (int tile = blockIdx.x; tile < NTILES; tile += gridDim.x) {
        int nb = tile * 64;
        __syncthreads();
        // ---- stage A1 ----
        if (A1BF) {
            const u16* A1b = (const u16*)A1v;
            for (int idx = t; idx < 64 * (K1 / 4); idx += 256) {
                int node = idx / (K1 / 4), kq = (idx % (K1 / 4)) * 4;
                int gn = nb + node;
                s4v v = {0, 0, 0, 0};
                if (gn < NN) {
                    v = *(const s4v*)(A1b + (size_t)gn * K1 + kq);
                    if (AAFF) {
#pragma unroll
                        for (int i = 0; i < 4; i++) {
                            float f = b2f((u16)v[i]) * aaff[kq + i] + aaff[64 + kq + i];
                            v[i] = (short)f2b(f);
                        }
                    }
                }
                *(s4v*)&A_lds[node * KP + kq] = v;
            }
        } else {
            const float* A1f = (const float*)A1v;
            for (int idx = t; idx < 64 * (K1 / 4); idx += 256) {
                int node = idx / (K1 / 4), kq = (idx % (K1 / 4)) * 4;
                int gn = nb + node;
                s4v v = {0, 0, 0, 0};
                if (gn < NN) {
                    float4 a = ld4(A1f + (size_t)gn * K1 + kq);
                    v[0] = (short)f2b(a.x); v[1] = (short)f2b(a.y);
                    v[2] = (short)f2b(a.z); v[3] = (short)f2b(a.w);
                }
                *(s4v*)&A_lds[node * KP + kq] = v;
            }
        }
        if (K2 > 0) {
            for (int idx = t; idx < 64 * (K2 / 4); idx += 256) {
                int node = idx / (K2 / 4), kq = (idx % (K2 / 4)) * 4;
                int gn = nb + node;
                s4v v = {0, 0, 0, 0};
                if (gn < NN) {
                    float4 a = ld4(A2 + (size_t)gn * K2 + kq);
                    v[0] = (short)f2b(a.x); v[1] = (short)f2b(a.y);
                    v[2] = (short)f2b(a.z); v[3] = (short)f2b(a.w);
                }
                *(s4v*)&A_lds[node * KP + K1 + kq] = v;
            }
        }
        __syncthreads();

        // ---- MFMA: wave wv -> nodes [nb+16wv, +16), all 64 ch ----
        f32x4 acc[4];
#pragma unroll
        for (int n = 0; n < 4; n++) acc[n] = (f32x4){0.f, 0.f, 0.f, 0.f};
        const int arow = 16 * wv + l15;
#pragma unroll
        for (int kk = 0; kk < K; kk += 32) {
            s4v alo = *(const s4v*)&A_lds[arow * KP + kk + lg * 4];
            s4v ahi = *(const s4v*)&A_lds[arow * KP + kk + lg * 4 + 16];
            bf16x8 a = __builtin_shufflevector(alo, ahi, 0, 1, 2, 3, 4, 5, 6, 7);
#pragma unroll
            for (int n = 0; n < 4; n++) {
                s4v blo = *(const s4v*)&Wt_lds[(16 * n + l15) * KP + kk + lg * 4];
                s4v bhi = *(const s4v*)&Wt_lds[(16 * n + l15) * KP + kk + lg * 4 + 16];
                bf16x8 b = __builtin_shufflevector(blo, bhi, 0, 1, 2, 3, 4, 5, 6, 7);
                acc[n] = __builtin_amdgcn_mfma_f32_16x16x32_bf16(a, b, acc[n], 0, 0, 0);
            }
        }

        // ---- epilogue ----
        float ss[4] = {0, 0, 0, 0}, sq2[4] = {0, 0, 0, 0};
#pragma unroll
        for (int r = 0; r < 4; r++) {
            int node = nb + 16 * wv + lg * 4 + r;
            if (node < NN) {
                float deg = BE ? (float)(row_ptr[node + 1] - row_ptr[node]) : 0.f;
                int nv = EMB ? nvi[node] : 0;
#pragma unroll
                for (int n = 0; n < 4; n++) {
                    int ch = 16 * n + l15;
                    float v = acc[n][r] + bias_c[n];
                    if (BE) v += deg * be_c[n];
                    if (EMB) v += emb[(size_t)nv * 64 + ch];
                    if (RESID) v += resid[(size_t)node * 64 + ch] * rsc_c[n] + rsh_c[n];
                    v = fmaxf(v, 0.f);
                    if (OUTF) Xf[(size_t)node * 64 + ch] = v;
                    if (OUTB) Xb[(size_t)node * 64 + ch] = f2b(v);
                    ss[n] += v;
                    sq2[n] += v * v;
                }
            }
        }
#pragma unroll
        for (int n = 0; n < 4; n++) {
            float a = ss[n];
            a += __shfl_xor(a, 16);
            a += __shfl_xor(a, 32);
            float b = sq2[n];
            b += __shfl_xor(b, 16);
            b += __shfl_xor(b, 32);
            if (lg == 0) {
                atomicAdd(&red[16 * n + l15], a);
                atomicAdd(&red[64 + 16 * n + l15], b);
            }
        }
    }
    __syncthreads();
    if (t < 128) atomicAdd(&stats[t], red[t]);
}

// ---------------- BN finalize ----------------
__global__ void kfin(float* __restrict__ stats, const float* __restrict__ g,
                     const float* __restrict__ b, int slot) {
    int t = threadIdx.x;  // 64
    float mean = stats[t] * (1.0f / NN);
    float var = stats[64 + t] * (1.0f / NN) - mean * mean;
    float rstd = rsqrtf(fmaxf(var, 0.f) + EPSBN);
    float sc = g[t] * rstd;
    float* slotp = stats + 128 + slot * 128;
    slotp[t] = sc;
    slotp[64 + t] = b[t] - mean * sc;
    stats[t] = 0.f;
    stats[64 + t] = 0.f;
}

// ---------------- message passing over packed bf16 h ----------------
__global__ void kmsg_bf(const u32* __restrict__ h2, const int* __restrict__ row_ptr,
                        const int* __restrict__ src, const float* __restrict__ aff,
                        u32* __restrict__ agg) {
    int lane = threadIdx.x & 63;
    int wid = threadIdx.x >> 6;
    int w = lane & 31, half = lane >> 5;
    float sc0 = aff[2 * w], sc1 = aff[2 * w + 1];
    float sh0 = aff[64 + 2 * w], sh1 = aff[64 + 2 * w + 1];
    for (int n = blockIdx.x * 4 + wid; n < NN; n += gridDim.x * 4) {
        int e0 = row_ptr[n], e1 = row_ptr[n + 1];
        float a0 = 0.f, a1 = 0.f;
        int e = e0;
        for (; e + 8 <= e1; e += 8) {
            int s0 = src[e + half], s1 = src[e + 2 + half];
            int s2 = src[e + 4 + half], s3 = src[e + 6 + half];
            u32 u0 = h2[(size_t)s0 * 32 + w];
            u32 u1 = h2[(size_t)s1 * 32 + w];
            u32 u2 = h2[(size_t)s2 * 32 + w];
            u32 u3 = h2[(size_t)s3 * 32 + w];
            a0 += (blo(u0) + blo(u1)) + (blo(u2) + blo(u3));
            a1 += (bhi(u0) + bhi(u1)) + (bhi(u2) + bhi(u3));
        }
        for (; e < e1; e += 2) {
            if (e + half < e1) {
                u32 u = h2[(size_t)src[e + half] * 32 + w];
                a0 += blo(u);
                a1 += bhi(u);
            }
        }
        a0 += __shfl_xor(a0, 32);
        a1 += __shfl_xor(a1, 32);
        if (half == 0) {
            float deg = (float)(e1 - e0);
            u16 o0 = f2b(sc0 * a0 + deg * sh0);
            u16 o1 = f2b(sc1 * a1 + deg * sh1);
            agg[(size_t)n * 32 + w] = (u32)o0 | ((u32)o1 << 16);
        }
    }
}

// ---------------- segmented max readout ----------------
__device__ __forceinline__ unsigned fenc(float f) {
    unsigned u = __float_as_uint(f);
    return (u >> 31) ? ~u : (u | 0x80000000u);
}
__device__ __forceinline__ float fdec(unsigned k) {
    return (k >> 31) ? __uint_as_float(k ^ 0x80000000u) : __uint_as_float(~k);
}

__global__ void kinitpk(unsigned* __restrict__ pk) {
    int i = blockIdx.x * blockDim.x + threadIdx.x;
    if (i < GG * DD) pk[i] = 0x007FFFFFu;
}

__global__ void kread(const float* __restrict__ h, const int* __restrict__ gidx,
                      const float* __restrict__ aff, unsigned* __restrict__ pk) {
    int lane = threadIdx.x & 63;
    int wid = threadIdx.x >> 6;
    float sc = aff[lane], sh = aff[64 + lane];
    int gw = blockIdx.x * 4 + wid;
    int nw = gridDim.x * 4;
    int chunk = (NN + nw - 1) / nw;
    int lo = gw * chunk, hi = min(lo + chunk, NN);
    if (lo >= hi) return;
    int cur = gidx[lo];
    float acc = -INFINITY;
    for (int n = lo; n < hi; n++) {
        int g = gidx[n];
        if (g != cur) {
            atomicMax(&pk[cur * DD + lane], fenc(acc));
            cur = g;
            acc = -INFINITY;
        }
        acc = fmaxf(acc, h[(size_t)n * 64 + lane] * sc + sh);
    }
    atomicMax(&pk[cur * DD + lane], fenc(acc));
}

__global__ void kout(const unsigned* __restrict__ pk, const float* __restrict__ W,
                     const float* __restrict__ b, float* __restrict__ out) {
    int t = blockIdx.x * blockDim.x + threadIdx.x;
    int g = t >> 6, d = t & 63;
    float acc = b[d];
    for (int k = 0; k < DD; k++) {
        float p = fdec(pk[g * DD + k]);
        acc += p * W[k * DD + d];
    }
    out[t] = fmaxf(acc, 0.f);
}

extern "C" void kernel_launch(void* const* d_in, const int* in_sizes, int n_in,
                              void* d_out, int out_size, void* d_ws, size_t ws_size,
                              hipStream_t stream) {
    const float* node_feat = (const float*)d_in[0];
    const float* edge_feat = (const float*)d_in[1];
    const float* w_n2l_W = (const float*)d_in[2];
    const float* w_n2l_b = (const float*)d_in[3];
    const float* nve = (const float*)d_in[4];
    const float* w_e2l_W = (const float*)d_in[5];
    const float* w_e2l_b = (const float*)d_in[6];
    const float* conv_W = (const float*)d_in[7];
    const float* conv_b = (const float*)d_in[8];
    const float* l2_W = (const float*)d_in[9];
    const float* l2_b = (const float*)d_in[10];
    const float* msg_g = (const float*)d_in[11];
    const float* msg_b = (const float*)d_in[12];
    const float* hid_g = (const float*)d_in[13];
    const float* hid_b = (const float*)d_in[14];
    const float* out_W = (const float*)d_in[15];
    const float* out_b = (const float*)d_in[16];
    const int* edge_from = (const int*)d_in[17];
    const int* edge_to = (const int*)d_in[18];
    const int* g_idx = (const int*)d_in[19];
    const int* nvi = (const int*)d_in[20];
    float* out = (float*)d_out;

    char* ws = (char*)d_ws;
    size_t off = 0;
    auto alloc = [&](size_t bytes) -> void* {
        void* p = ws + off;
        off += (bytes + 255) / 256 * 256;
        return p;
    };
    int* cnt = (int*)alloc((size_t)NN * 4);
    int* row_ptr = (int*)alloc((size_t)(NN + 1) * 4);
    int* cursor = (int*)alloc((size_t)NN * 4);
    int* eid = (int*)alloc((size_t)EE * 4);
    int* srcarr = (int*)alloc((size_t)EE * 4);
    float* pooled_ef = (float*)alloc((size_t)NN * EF * 4);
    float* hb0 = (float*)alloc((size_t)NN * DD * 4);
    float* hb1 = (float*)alloc((size_t)NN * DD * 4);
    u16* h2 = (u16*)alloc((size_t)NN * DD * 2);
    u16* agg_bf = (u16*)alloc((size_t)NN * DD * 2);
    u16* mb_bf = (u16*)alloc((size_t)NN * DD * 2);
    float* stats = (float*)alloc(1024 * 4);
    unsigned* pk = (unsigned*)alloc((size_t)GG * DD * 4);
    int* bsum = (int*)alloc((size_t)NBS * 4);
    int* boff = (int*)alloc((size_t)512 * 4);
    (void)ws_size; (void)n_in; (void)in_sizes; (void)out_size;

    hipMemsetAsync(cnt, 0, (size_t)NN * 4, stream);
    hipMemsetAsync(stats, 0, 1024 * 4, stream);
    kinitpk<<<16, 256, 0, stream>>>(pk);

    khist<<<(EE + 255) / 256, 256, 0, stream>>>(edge_to, cnt);
    kbsum<<<NBS, 256, 0, stream>>>(cnt, bsum);
    kbscan<<<1, 512, 0, stream>>>(bsum, boff);
    kfscan<<<NBS, 256, 0, stream>>>(cnt, boff, row_ptr, cursor);
    kreorder<<<(EE + 255) / 256, 256, 0, stream>>>(edge_to, edge_from, cursor, eid, srcarr);
    kpool<<<2048, 256, 0, stream>>>(edge_feat, row_ptr, eid, pooled_ef);

    // h0 = relu(node_feat@W + b + emb + pooled@We0 + deg*be0); -> hb0 (f32) + h2 (bf16)
    kgemm_mfma<NF, EF, false, false, true, true, false, true, true>
        <<<NTILES, 256, 0, stream>>>(node_feat, pooled_ef, w_n2l_W, w_e2l_W,
                                     w_n2l_b, w_e2l_b, row_ptr, nve, nvi,
                                     nullptr, nullptr, nullptr, hb0, h2, stats);
    kfin<<<1, 64, 0, stream>>>(stats, msg_g, msg_b, 0);

    float* hcur = hb0;
    float* hnext = hb1;
    for (int lv = 0; lv < LVL; lv++) {
        kmsg_bf<<<2048, 256, 0, stream>>>((const u32*)h2, row_ptr, srcarr,
                                          stats + 128 + lv * 128, (u32*)agg_bf);
        // merged_raw = relu(agg@cW + cb + pooled@We + deg*be) -> mb_bf
        kgemm_mfma<DD, EF, true, false, false, true, false, false, true>
            <<<NTILES, 256, 0, stream>>>(agg_bf, pooled_ef, conv_W + lv * DD * DD,
                                         w_e2l_W + (size_t)(lv + 1) * EF * DD,
                                         conv_b + lv * DD,
                                         w_e2l_b + (size_t)(lv + 1) * DD, row_ptr,
                                         nullptr, nullptr, nullptr, nullptr, nullptr,
                                         nullptr, mb_bf, stats);
        kfin<<<1, 64, 0, stream>>>(stats, hid_g + lv * DD, hid_b + lv * DD, 4 + lv);
        // hnext = relu(bn(merged)@l2W + l2b + bn(hcur)) -> hnext (f32) + h2 (bf16)
        kgemm_mfma<DD, 0, true, true, false, false, true, true, true>
            <<<NTILES, 256, 0, stream>>>(mb_bf, nullptr, l2_W + lv * DD * DD, nullptr,
                                         l2_b + lv * DD, nullptr, row_ptr, nullptr,
                                         nullptr, hcur, stats + 128 + lv * 128,
                                         stats + 128 + (4 + lv) * 128, hnext, h2, stats);
        kfin<<<1, 64, 0, stream>>>(stats, msg_g + (lv + 1) * DD, msg_b + (lv + 1) * DD,
                                   lv + 1);
        float* tmp = hcur; hcur = hnext; hnext = tmp;
    }

    kread<<<1024, 256, 0, stream>>>(hcur, g_idx, stats + 128 + LVL * 128, pk);
    kout<<<GG, 64, 0, stream>>>(pk, out_W, out_b, out);
}

// Round 5
// 710.096 us; speedup vs baseline: 3.1437x; 1.1580x over previous
//
#include <hip/hip_runtime.h>
#include <math.h>

#define NN 100000
#define EE 1600000
#define GG 64
#define DD 64
#define NF 128
#define EF 32
#define LVL 3
#define EPSBN 1e-5f
#define NTILES ((NN + 63) / 64)
#define NBS ((NN + 255) / 256)

typedef unsigned short u16;
typedef unsigned int u32;
typedef short s4v __attribute__((ext_vector_type(4)));
typedef short bf16x8 __attribute__((ext_vector_type(8)));
typedef float f32x4 __attribute__((ext_vector_type(4)));

__device__ __forceinline__ float4 ld4(const float* p) { return *(const float4*)p; }
__device__ __forceinline__ u16 f2b(float f) {
    u32 u = __float_as_uint(f);
    return (u16)((u + 0x7FFFu + ((u >> 16) & 1u)) >> 16);
}
__device__ __forceinline__ float b2f(u16 u) { return __uint_as_float(((u32)u) << 16); }
__device__ __forceinline__ float blo(u32 u) { return __uint_as_float(u << 16); }
__device__ __forceinline__ float bhi(u32 u) { return __uint_as_float(u & 0xFFFF0000u); }

// ---------------- CSR build ----------------
__global__ void khist(const int* __restrict__ to, int* __restrict__ cnt) {
    int e = blockIdx.x * blockDim.x + threadIdx.x;
    if (e < EE) atomicAdd(&cnt[to[e]], 1);
}

__global__ void kbsum(const int* __restrict__ cnt, int* __restrict__ bsum) {
    __shared__ int s[256];
    int t = threadIdx.x;
    int i = blockIdx.x * 256 + t;
    s[t] = (i < NN) ? cnt[i] : 0;
    __syncthreads();
    for (int off = 128; off > 0; off >>= 1) {
        if (t < off) s[t] += s[t + off];
        __syncthreads();
    }
    if (t == 0) bsum[blockIdx.x] = s[0];
}

__global__ void kbscan(const int* __restrict__ bsum, int* __restrict__ boff) {
    __shared__ int s[512];
    int t = threadIdx.x;
    s[t] = (t < NBS) ? bsum[t] : 0;
    __syncthreads();
    for (int off = 1; off < 512; off <<= 1) {
        int v = (t >= off) ? s[t - off] : 0;
        __syncthreads();
        s[t] += v;
        __syncthreads();
    }
    if (t < NBS) boff[t] = (t == 0) ? 0 : s[t - 1];
}

__global__ void kfscan(const int* __restrict__ cnt, const int* __restrict__ boff,
                       int* __restrict__ row_ptr, int* __restrict__ cursor) {
    __shared__ int s[256];
    int t = threadIdx.x;
    int b = blockIdx.x;
    int i = b * 256 + t;
    int v = (i < NN) ? cnt[i] : 0;
    s[t] = v;
    __syncthreads();
    for (int off = 1; off < 256; off <<= 1) {
        int u = (t >= off) ? s[t - off] : 0;
        __syncthreads();
        s[t] += u;
        __syncthreads();
    }
    if (i < NN) {
        int excl = boff[b] + s[t] - v;
        row_ptr[i] = excl;
        cursor[i] = excl;
        if (i == NN - 1) row_ptr[NN] = boff[b] + s[t];
    }
}

// write (edge_id, src) as one 8-byte scatter
__global__ void kreorder(const int* __restrict__ to, const int* __restrict__ from,
                         int* __restrict__ cursor, int2* __restrict__ pair) {
    int e = blockIdx.x * blockDim.x + threadIdx.x;
    if (e < EE) {
        int pos = atomicAdd(&cursor[to[e]], 1);
        pair[pos] = make_int2(e, from[e]);
    }
}

// ---------------- edge-feature pooling -> packed bf16 ----------------
// wave per node: lanes = 2 edges x 32 channels
__global__ void kpool(const float* __restrict__ ef, const int* __restrict__ row_ptr,
                      const int2* __restrict__ pair, u16* __restrict__ pooled) {
    int lane = threadIdx.x & 63;
    int wid = threadIdx.x >> 6;
    int w = lane & 31, half = lane >> 5;
    for (int n = blockIdx.x * 4 + wid; n < NN; n += gridDim.x * 4) {
        int e0 = row_ptr[n], e1 = row_ptr[n + 1];
        float acc = 0.f;
        int e = e0 + half;
        for (; e + 2 < e1; e += 4) {
            int i0 = pair[e].x, i1 = pair[e + 2].x;
            float v0 = ef[(size_t)i0 * EF + w];
            float v1 = ef[(size_t)i1 * EF + w];
            acc += v0 + v1;
        }
        if (e < e1) acc += ef[(size_t)pair[e].x * EF + w];
        acc += __shfl_xor(acc, 32);
        if (half == 0) pooled[(size_t)n * EF + w] = f2b(acc);
    }
}

// ---------------- MFMA bf16 fused GEMM ----------------
// out = relu([A1|A2]@[W1;W2] + bias + deg*be + emb[nvi] + b2f(resid)*rsc+rsh) -> bf16 Xb + stats
template <int K1, int K2, bool A1BF, bool AAFF, bool EMB, bool BE, bool RESID>
__global__ __launch_bounds__(256) void kgemm_mfma(
    const void* __restrict__ A1v, const u16* __restrict__ A2,
    const float* __restrict__ W1, const float* __restrict__ W2,
    const float* __restrict__ bias, const float* __restrict__ be,
    const int* __restrict__ row_ptr, const float* __restrict__ emb,
    const int* __restrict__ nvi, const u16* __restrict__ resid,
    const float* __restrict__ raff, const float* __restrict__ aaff,
    u16* __restrict__ Xb, float* __restrict__ stats) {
    constexpr int K = K1 + K2;
    constexpr int KP = K + 8;
    __shared__ u16 A_lds[64 * KP];
    __shared__ u16 Wt_lds[64 * KP];
    __shared__ float red[128];

    const int t = threadIdx.x;
    const int lane = t & 63;
    const int wv = t >> 6;
    const int l15 = lane & 15;
    const int lg = lane >> 4;

    for (int idx = t; idx < K * 16; idx += 256) {
        int k = idx >> 4, c4 = (idx & 15) * 4;
        float4 w4 = (k < K1) ? ld4(W1 + (size_t)k * 64 + c4)
                             : ld4(W2 + (size_t)(k - K1) * 64 + c4);
        Wt_lds[(c4 + 0) * KP + k] = f2b(w4.x);
        Wt_lds[(c4 + 1) * KP + k] = f2b(w4.y);
        Wt_lds[(c4 + 2) * KP + k] = f2b(w4.z);
        Wt_lds[(c4 + 3) * KP + k] = f2b(w4.w);
    }
    if (t < 128) red[t] = 0.f;

    float bias_c[4], be_c[4], rsc_c[4], rsh_c[4];
#pragma unroll
    for (int n = 0; n < 4; n++) {
        int ch = 16 * n + l15;
        bias_c[n] = bias[ch];
        be_c[n] = BE ? be[ch] : 0.f;
        rsc_c[n] = RESID ? raff[ch] : 0.f;
        rsh_c[n] = RESID ? raff[64 + ch] : 0.f;
    }

    for (int tile = blockIdx.x; tile < NTILES; tile += gridDim.x) {
        int nb = tile * 64;
        __syncthreads();
        if (A1BF) {
            const u16* A1b = (const u16*)A1v;
            for (int idx = t; idx < 64 * (K1 / 4); idx += 256) {
                int node = idx / (K1 / 4), kq = (idx % (K1 / 4)) * 4;
                int gn = nb + node;
                s4v v = {0, 0, 0, 0};
                if (gn < NN) {
                    v = *(const s4v*)(A1b + (size_t)gn * K1 + kq);
                    if (AAFF) {
#pragma unroll
                        for (int i = 0; i < 4; i++) {
                            float f = b2f((u16)v[i]) * aaff[kq + i] + aaff[64 + kq + i];
                            v[i] = (short)f2b(f);
                        }
                    }
                }
                *(s4v*)&A_lds[node * KP + kq] = v;
            }
        } else {
            const float* A1f = (const float*)A1v;
            for (int idx = t; idx < 64 * (K1 / 4); idx += 256) {
                int node = idx / (K1 / 4), kq = (idx % (K1 / 4)) * 4;
                int gn = nb + node;
                s4v v = {0, 0, 0, 0};
                if (gn < NN) {
                    float4 a = ld4(A1f + (size_t)gn * K1 + kq);
                    v[0] = (short)f2b(a.x); v[1] = (short)f2b(a.y);
                    v[2] = (short)f2b(a.z); v[3] = (short)f2b(a.w);
                }
                *(s4v*)&A_lds[node * KP + kq] = v;
            }
        }
        if (K2 > 0) {
            for (int idx = t; idx < 64 * (K2 / 4); idx += 256) {
                int node = idx / (K2 / 4), kq = (idx % (K2 / 4)) * 4;
                int gn = nb + node;
                s4v v = {0, 0, 0, 0};
                if (gn < NN) v = *(const s4v*)(A2 + (size_t)gn * K2 + kq);
                *(s4v*)&A_lds[node * KP + K1 + kq] = v;
            }
        }
        __syncthreads();

        f32x4 acc[4];
#pragma unroll
        for (int n = 0; n < 4; n++) acc[n] = (f32x4){0.f, 0.f, 0.f, 0.f};
        const int arow = 16 * wv + l15;
#pragma unroll
        for (int kk = 0; kk < K; kk += 32) {
            s4v alo = *(const s4v*)&A_lds[arow * KP + kk + lg * 4];
            s4v ahi = *(const s4v*)&A_lds[arow * KP + kk + lg * 4 + 16];
            bf16x8 a = __builtin_shufflevector(alo, ahi, 0, 1, 2, 3, 4, 5, 6, 7);
#pragma unroll
            for (int n = 0; n < 4; n++) {
                s4v wlo = *(const s4v*)&Wt_lds[(16 * n + l15) * KP + kk + lg * 4];
                s4v whi = *(const s4v*)&Wt_lds[(16 * n + l15) * KP + kk + lg * 4 + 16];
                bf16x8 b = __builtin_shufflevector(wlo, whi, 0, 1, 2, 3, 4, 5, 6, 7);
                acc[n] = __builtin_amdgcn_mfma_f32_16x16x32_bf16(a, b, acc[n], 0, 0, 0);
            }
        }

        float ss[4] = {0, 0, 0, 0}, sq2[4] = {0, 0, 0, 0};
#pragma unroll
        for (int r = 0; r < 4; r++) {
            int node = nb + 16 * wv + lg * 4 + r;
            if (node < NN) {
                float deg = BE ? (float)(row_ptr[node + 1] - row_ptr[node]) : 0.f;
                int nv = EMB ? nvi[node] : 0;
#pragma unroll
                for (int n = 0; n < 4; n++) {
                    int ch = 16 * n + l15;
                    float v = acc[n][r] + bias_c[n];
                    if (BE) v += deg * be_c[n];
                    if (EMB) v += emb[(size_t)nv * 64 + ch];
                    if (RESID) v += b2f(resid[(size_t)node * 64 + ch]) * rsc_c[n] + rsh_c[n];
                    v = fmaxf(v, 0.f);
                    Xb[(size_t)node * 64 + ch] = f2b(v);
                    ss[n] += v;
                    sq2[n] += v * v;
                }
            }
        }
#pragma unroll
        for (int n = 0; n < 4; n++) {
            float a = ss[n];
            a += __shfl_xor(a, 16);
            a += __shfl_xor(a, 32);
            float b = sq2[n];
            b += __shfl_xor(b, 16);
            b += __shfl_xor(b, 32);
            if (lg == 0) {
                atomicAdd(&red[16 * n + l15], a);
                atomicAdd(&red[64 + 16 * n + l15], b);
            }
        }
    }
    __syncthreads();
    if (t < 128) atomicAdd(&stats[t], red[t]);
}

// ---------------- BN finalize ----------------
__global__ void kfin(float* __restrict__ stats, const float* __restrict__ g,
                     const float* __restrict__ b, int slot) {
    int t = threadIdx.x;  // 64
    float mean = stats[t] * (1.0f / NN);
    float var = stats[64 + t] * (1.0f / NN) - mean * mean;
    float rstd = rsqrtf(fmaxf(var, 0.f) + EPSBN);
    float sc = g[t] * rstd;
    float* slotp = stats + 128 + slot * 128;
    slotp[t] = sc;
    slotp[64 + t] = b[t] - mean * sc;
    stats[t] = 0.f;
    stats[64 + t] = 0.f;
}

// ---------------- message passing over packed bf16 h ----------------
__global__ void kmsg_bf(const u32* __restrict__ h2, const int* __restrict__ row_ptr,
                        const int2* __restrict__ pair, const float* __restrict__ aff,
                        u32* __restrict__ agg) {
    int lane = threadIdx.x & 63;
    int wid = threadIdx.x >> 6;
    int w = lane & 31, half = lane >> 5;
    float sc0 = aff[2 * w], sc1 = aff[2 * w + 1];
    float sh0 = aff[64 + 2 * w], sh1 = aff[64 + 2 * w + 1];
    for (int n = blockIdx.x * 4 + wid; n < NN; n += gridDim.x * 4) {
        int e0 = row_ptr[n], e1 = row_ptr[n + 1];
        float a0 = 0.f, a1 = 0.f;
        int e = e0;
        for (; e + 16 <= e1; e += 16) {
            int s0 = pair[e + half].y, s1 = pair[e + 2 + half].y;
            int s2 = pair[e + 4 + half].y, s3 = pair[e + 6 + half].y;
            int s4 = pair[e + 8 + half].y, s5 = pair[e + 10 + half].y;
            int s6 = pair[e + 12 + half].y, s7 = pair[e + 14 + half].y;
            u32 u0 = h2[(size_t)s0 * 32 + w];
            u32 u1 = h2[(size_t)s1 * 32 + w];
            u32 u2 = h2[(size_t)s2 * 32 + w];
            u32 u3 = h2[(size_t)s3 * 32 + w];
            u32 u4 = h2[(size_t)s4 * 32 + w];
            u32 u5 = h2[(size_t)s5 * 32 + w];
            u32 u6 = h2[(size_t)s6 * 32 + w];
            u32 u7 = h2[(size_t)s7 * 32 + w];
            a0 += ((blo(u0) + blo(u1)) + (blo(u2) + blo(u3))) +
                  ((blo(u4) + blo(u5)) + (blo(u6) + blo(u7)));
            a1 += ((bhi(u0) + bhi(u1)) + (bhi(u2) + bhi(u3))) +
                  ((bhi(u4) + bhi(u5)) + (bhi(u6) + bhi(u7)));
        }
        for (; e + 8 <= e1; e += 8) {
            int s0 = pair[e + half].y, s1 = pair[e + 2 + half].y;
            int s2 = pair[e + 4 + half].y, s3 = pair[e + 6 + half].y;
            u32 u0 = h2[(size_t)s0 * 32 + w];
            u32 u1 = h2[(size_t)s1 * 32 + w];
            u32 u2 = h2[(size_t)s2 * 32 + w];
            u32 u3 = h2[(size_t)s3 * 32 + w];
            a0 += (blo(u0) + blo(u1)) + (blo(u2) + blo(u3));
            a1 += (bhi(u0) + bhi(u1)) + (bhi(u2) + bhi(u3));
        }
        for (; e < e1; e += 2) {
            if (e + half < e1) {
                u32 u = h2[(size_t)pair[e + half].y * 32 + w];
                a0 += blo(u);
                a1 += bhi(u);
            }
        }
        a0 += __shfl_xor(a0, 32);
        a1 += __shfl_xor(a1, 32);
        if (half == 0) {
            float deg = (float)(e1 - e0);
            u16 o0 = f2b(sc0 * a0 + deg * sh0);
            u16 o1 = f2b(sc1 * a1 + deg * sh1);
            agg[(size_t)n * 32 + w] = (u32)o0 | ((u32)o1 << 16);
        }
    }
}

// ---------------- segmented max readout ----------------
__device__ __forceinline__ unsigned fenc(float f) {
    unsigned u = __float_as_uint(f);
    return (u >> 31) ? ~u : (u | 0x80000000u);
}
__device__ __forceinline__ float fdec(unsigned k) {
    return (k >> 31) ? __uint_as_float(k ^ 0x80000000u) : __uint_as_float(~k);
}

__global__ void kinitpk(unsigned* __restrict__ pk) {
    int i = blockIdx.x * blockDim.x + threadIdx.x;
    if (i < GG * DD) pk[i] = 0x007FFFFFu;
}

__global__ void kread(const u16* __restrict__ h2, const int* __restrict__ gidx,
                      const float* __restrict__ aff, unsigned* __restrict__ pk) {
    int lane = threadIdx.x & 63;
    int wid = threadIdx.x >> 6;
    float sc = aff[lane], sh = aff[64 + lane];
    int gw = blockIdx.x * 4 + wid;
    int nw = gridDim.x * 4;
    int chunk = (NN + nw - 1) / nw;
    int lo = gw * chunk, hi = min(lo + chunk, NN);
    if (lo >= hi) return;
    int cur = gidx[lo];
    float acc = -INFINITY;
    for (int n = lo; n < hi; n++) {
        int g = gidx[n];
        if (g != cur) {
            atomicMax(&pk[cur * DD + lane], fenc(acc));
            cur = g;
            acc = -INFINITY;
        }
        acc = fmaxf(acc, b2f(h2[(size_t)n * 64 + lane]) * sc + sh);
    }
    atomicMax(&pk[cur * DD + lane], fenc(acc));
}

__global__ void kout(const unsigned* __restrict__ pk, const float* __restrict__ W,
                     const float* __restrict__ b, float* __restrict__ out) {
    int t = blockIdx.x * blockDim.x + threadIdx.x;
    int g = t >> 6, d = t & 63;
    float acc = b[d];
    for (int k = 0; k < DD; k++) {
        float p = fdec(pk[g * DD + k]);
        acc += p * W[k * DD + d];
    }
    out[t] = fmaxf(acc, 0.f);
}

extern "C" void kernel_launch(void* const* d_in, const int* in_sizes, int n_in,
                              void* d_out, int out_size, void* d_ws, size_t ws_size,
                              hipStream_t stream) {
    const float* node_feat = (const float*)d_in[0];
    const float* edge_feat = (const float*)d_in[1];
    const float* w_n2l_W = (const float*)d_in[2];
    const float* w_n2l_b = (const float*)d_in[3];
    const float* nve = (const float*)d_in[4];
    const float* w_e2l_W = (const float*)d_in[5];
    const float* w_e2l_b = (const float*)d_in[6];
    const float* conv_W = (const float*)d_in[7];
    const float* conv_b = (const float*)d_in[8];
    const float* l2_W = (const float*)d_in[9];
    const float* l2_b = (const float*)d_in[10];
    const float* msg_g = (const float*)d_in[11];
    const float* msg_b = (const float*)d_in[12];
    const float* hid_g = (const float*)d_in[13];
    const float* hid_b = (const float*)d_in[14];
    const float* out_W = (const float*)d_in[15];
    const float* out_b = (const float*)d_in[16];
    const int* edge_from = (const int*)d_in[17];
    const int* edge_to = (const int*)d_in[18];
    const int* g_idx = (const int*)d_in[19];
    const int* nvi = (const int*)d_in[20];
    float* out = (float*)d_out;

    char* ws = (char*)d_ws;
    size_t off = 0;
    auto alloc = [&](size_t bytes) -> void* {
        void* p = ws + off;
        off += (bytes + 255) / 256 * 256;
        return p;
    };
    int* cnt = (int*)alloc((size_t)NN * 4);
    int* row_ptr = (int*)alloc((size_t)(NN + 1) * 4);
    int* cursor = (int*)alloc((size_t)NN * 4);
    int2* pair = (int2*)alloc((size_t)EE * 8);
    u16* pooled_ef = (u16*)alloc((size_t)NN * EF * 2);
    u16* h2a = (u16*)alloc((size_t)NN * DD * 2);
    u16* h2b = (u16*)alloc((size_t)NN * DD * 2);
    u16* agg_bf = (u16*)alloc((size_t)NN * DD * 2);
    u16* mb_bf = (u16*)alloc((size_t)NN * DD * 2);
    float* stats = (float*)alloc(1024 * 4);
    unsigned* pk = (unsigned*)alloc((size_t)GG * DD * 4);
    int* bsum = (int*)alloc((size_t)NBS * 4);
    int* boff = (int*)alloc((size_t)512 * 4);
    (void)ws_size; (void)n_in; (void)in_sizes; (void)out_size;

    hipMemsetAsync(cnt, 0, (size_t)NN * 4, stream);
    hipMemsetAsync(stats, 0, 1024 * 4, stream);
    kinitpk<<<16, 256, 0, stream>>>(pk);

    khist<<<(EE + 255) / 256, 256, 0, stream>>>(edge_to, cnt);
    kbsum<<<NBS, 256, 0, stream>>>(cnt, bsum);
    kbscan<<<1, 512, 0, stream>>>(bsum, boff);
    kfscan<<<NBS, 256, 0, stream>>>(cnt, boff, row_ptr, cursor);
    kreorder<<<(EE + 255) / 256, 256, 0, stream>>>(edge_to, edge_from, cursor, pair);
    kpool<<<2048, 256, 0, stream>>>(edge_feat, row_ptr, pair, pooled_ef);

    const int GB = 782;

    // h0 -> h2a
    kgemm_mfma<NF, EF, false, false, true, true, false>
        <<<GB, 256, 0, stream>>>(node_feat, pooled_ef, w_n2l_W, w_e2l_W,
                                 w_n2l_b, w_e2l_b, row_ptr, nve, nvi,
                                 nullptr, nullptr, nullptr, h2a, stats);
    kfin<<<1, 64, 0, stream>>>(stats, msg_g, msg_b, 0);

    u16* hcur = h2a;
    u16* hnext = h2b;
    for (int lv = 0; lv < LVL; lv++) {
        kmsg_bf<<<2048, 256, 0, stream>>>((const u32*)hcur, row_ptr, pair,
                                          stats + 128 + lv * 128, (u32*)agg_bf);
        kgemm_mfma<DD, EF, true, false, false, true, false>
            <<<GB, 256, 0, stream>>>(agg_bf, pooled_ef, conv_W + lv * DD * DD,
                                     w_e2l_W + (size_t)(lv + 1) * EF * DD,
                                     conv_b + lv * DD,
                                     w_e2l_b + (size_t)(lv + 1) * DD, row_ptr,
                                     nullptr, nullptr, nullptr, nullptr, nullptr,
                                     mb_bf, stats);
        kfin<<<1, 64, 0, stream>>>(stats, hid_g + lv * DD, hid_b + lv * DD, 4 + lv);
        kgemm_mfma<DD, 0, true, true, false, false, true>
            <<<GB, 256, 0, stream>>>(mb_bf, nullptr, l2_W + lv * DD * DD, nullptr,
                                     l2_b + lv * DD, nullptr, row_ptr, nullptr,
                                     nullptr, hcur, stats + 128 + lv * 128,
                                     stats + 128 + (4 + lv) * 128, hnext, stats);
        kfin<<<1, 64, 0, stream>>>(stats, msg_g + (lv + 1) * DD, msg_b + (lv + 1) * DD,
                                   lv + 1);
        u16* tmp = hcur; hcur = hnext; hnext = tmp;
    }

    kread<<<1024, 256, 0, stream>>>(hcur, g_idx, stats + 128 + LVL * 128, pk);
    kout<<<GG, 64, 0, stream>>>(pk, out_W, out_b, out);
}

// Round 6
// 584.498 us; speedup vs baseline: 3.8192x; 1.2149x over previous
//
#include <hip/hip_runtime.h>
#include <math.h>

#define NN 100000
#define EE 1600000
#define GG 64
#define DD 64
#define NF 128
#define EF 32
#define LVL 3
#define EPSBN 1e-5f
#define NTILES ((NN + 63) / 64)
#define NBKT 391  // ceil(NN / 256)

typedef unsigned short u16;
typedef unsigned int u32;
typedef short s4v __attribute__((ext_vector_type(4)));
typedef short bf16x8 __attribute__((ext_vector_type(8)));
typedef float f32x4 __attribute__((ext_vector_type(4)));

__device__ __forceinline__ float4 ld4(const float* p) { return *(const float4*)p; }
__device__ __forceinline__ u16 f2b(float f) {
    u32 u = __float_as_uint(f);
    return (u16)((u + 0x7FFFu + ((u >> 16) & 1u)) >> 16);
}
__device__ __forceinline__ float b2f(u16 u) { return __uint_as_float(((u32)u) << 16); }
__device__ __forceinline__ float blo(u32 u) { return __uint_as_float(u << 16); }
__device__ __forceinline__ float bhi(u32 u) { return __uint_as_float(u & 0xFFFF0000u); }

// ---------------- CSR build: two-level bucket sort ----------------
// bucket b covers nodes [256b, 256b+256)

// pass 1a: global bucket histogram (LDS-aggregated)
__global__ void k1b(const int* __restrict__ to, int* __restrict__ bhist) {
    __shared__ int h[NBKT];
    for (int i = threadIdx.x; i < NBKT; i += 256) h[i] = 0;
    __syncthreads();
    for (int e = blockIdx.x * 256 + threadIdx.x; e < EE; e += 256 * gridDim.x)
        atomicAdd(&h[to[e] >> 8], 1);
    __syncthreads();
    for (int i = threadIdx.x; i < NBKT; i += 256)
        if (h[i]) atomicAdd(&bhist[i], h[i]);
}

// pass 1b: scan bucket sizes -> bbase, init gcur
__global__ void k1c(const int* __restrict__ bhist, int* __restrict__ bbase,
                    int* __restrict__ gcur) {
    __shared__ int s[512];
    int t = threadIdx.x;
    s[t] = (t < NBKT) ? bhist[t] : 0;
    __syncthreads();
    for (int off = 1; off < 512; off <<= 1) {
        int v = (t >= off) ? s[t - off] : 0;
        __syncthreads();
        s[t] += v;
        __syncthreads();
    }
    if (t < NBKT) {
        int base = t ? s[t - 1] : 0;
        bbase[t] = base;
        gcur[t] = base;
    }
    if (t == NBKT - 1) bbase[NBKT] = s[t];
}

// pass 1c: partition edges into bucket-contiguous tmp
// tmp word0 = from | (rel_to << 17), word1 = edge id
__global__ void k1d(const int* __restrict__ to, const int* __restrict__ from,
                    int* __restrict__ gcur, int2* __restrict__ tmp) {
    __shared__ int h[NBKT];
    __shared__ int cur[NBKT];
    for (int i = threadIdx.x; i < NBKT; i += 256) h[i] = 0;
    __syncthreads();
    for (int e = blockIdx.x * 256 + threadIdx.x; e < EE; e += 256 * gridDim.x)
        atomicAdd(&h[to[e] >> 8], 1);
    __syncthreads();
    for (int i = threadIdx.x; i < NBKT; i += 256)
        cur[i] = h[i] ? atomicAdd(&gcur[i], h[i]) : 0;
    __syncthreads();
    for (int e = blockIdx.x * 256 + threadIdx.x; e < EE; e += 256 * gridDim.x) {
        int tt = to[e];
        int b = tt >> 8;
        int pos = atomicAdd(&cur[b], 1);
        tmp[pos] = make_int2(from[e] | ((tt & 255) << 17), e);
    }
}

// pass 2: per-bucket block: per-node LDS histogram+scan -> row_ptr; scatter pair
__global__ void kp2(const int2* __restrict__ tmp, const int* __restrict__ bbase,
                    int* __restrict__ row_ptr, int2* __restrict__ pair) {
    __shared__ int s[256];
    __shared__ int cur[256];
    int b = blockIdx.x, t = threadIdx.x;
    int e0 = bbase[b], e1 = bbase[b + 1];
    s[t] = 0;
    __syncthreads();
    for (int e = e0 + t; e < e1; e += 256) atomicAdd(&s[(tmp[e].x >> 17) & 255], 1);
    __syncthreads();
    int v = s[t];
    for (int off = 1; off < 256; off <<= 1) {
        int u = (t >= off) ? s[t - off] : 0;
        __syncthreads();
        s[t] += u;
        __syncthreads();
    }
    int excl = e0 + s[t] - v;
    cur[t] = excl;
    int n = b * 256 + t;
    if (n < NN) row_ptr[n] = excl;
    if (b == NBKT - 1 && t == 0) row_ptr[NN] = e1;
    __syncthreads();
    for (int e = e0 + t; e < e1; e += 256) {
        int2 w = tmp[e];
        int pos = atomicAdd(&cur[(w.x >> 17) & 255], 1);
        pair[pos] = make_int2(w.y, w.x & 0x1FFFF);
    }
}

// ---------------- edge-feature pooling -> packed bf16 ----------------
__global__ void kpool(const float* __restrict__ ef, const int* __restrict__ row_ptr,
                      const int2* __restrict__ pair, u16* __restrict__ pooled) {
    int lane = threadIdx.x & 63;
    int wid = threadIdx.x >> 6;
    int w = lane & 31, half = lane >> 5;
    for (int n = blockIdx.x * 4 + wid; n < NN; n += gridDim.x * 4) {
        int e0 = row_ptr[n], e1 = row_ptr[n + 1];
        float acc = 0.f;
        int e = e0 + half;
        for (; e + 6 < e1; e += 8) {
            int i0 = pair[e].x, i1 = pair[e + 2].x;
            int i2 = pair[e + 4].x, i3 = pair[e + 6].x;
            float v0 = ef[(size_t)i0 * EF + w];
            float v1 = ef[(size_t)i1 * EF + w];
            float v2 = ef[(size_t)i2 * EF + w];
            float v3 = ef[(size_t)i3 * EF + w];
            acc += (v0 + v1) + (v2 + v3);
        }
        for (; e < e1; e += 2) acc += ef[(size_t)pair[e].x * EF + w];
        acc += __shfl_xor(acc, 32);
        if (half == 0) pooled[(size_t)n * EF + w] = f2b(acc);
    }
}

// ---------------- MFMA bf16 fused GEMM ----------------
template <int K1, int K2, bool A1BF, bool AAFF, bool EMB, bool BE, bool RESID>
__global__ __launch_bounds__(256) void kgemm_mfma(
    const void* __restrict__ A1v, const u16* __restrict__ A2,
    const float* __restrict__ W1, const float* __restrict__ W2,
    const float* __restrict__ bias, const float* __restrict__ be,
    const int* __restrict__ row_ptr, const float* __restrict__ emb,
    const int* __restrict__ nvi, const u16* __restrict__ resid,
    const float* __restrict__ raff, const float* __restrict__ aaff,
    u16* __restrict__ Xb, float* __restrict__ stats) {
    constexpr int K = K1 + K2;
    constexpr int KP = K + 8;
    __shared__ u16 A_lds[64 * KP];
    __shared__ u16 Wt_lds[64 * KP];
    __shared__ float red[128];

    const int t = threadIdx.x;
    const int lane = t & 63;
    const int wv = t >> 6;
    const int l15 = lane & 15;
    const int lg = lane >> 4;

    for (int idx = t; idx < K * 16; idx += 256) {
        int k = idx >> 4, c4 = (idx & 15) * 4;
        float4 w4 = (k < K1) ? ld4(W1 + (size_t)k * 64 + c4)
                             : ld4(W2 + (size_t)(k - K1) * 64 + c4);
        Wt_lds[(c4 + 0) * KP + k] = f2b(w4.x);
        Wt_lds[(c4 + 1) * KP + k] = f2b(w4.y);
        Wt_lds[(c4 + 2) * KP + k] = f2b(w4.z);
        Wt_lds[(c4 + 3) * KP + k] = f2b(w4.w);
    }
    if (t < 128) red[t] = 0.f;

    float bias_c[4], be_c[4], rsc_c[4], rsh_c[4];
#pragma unroll
    for (int n = 0; n < 4; n++) {
        int ch = 16 * n + l15;
        bias_c[n] = bias[ch];
        be_c[n] = BE ? be[ch] : 0.f;
        rsc_c[n] = RESID ? raff[ch] : 0.f;
        rsh_c[n] = RESID ? raff[64 + ch] : 0.f;
    }

    for (int tile = blockIdx.x; tile < NTILES; tile += gridDim.x) {
        int nb = tile * 64;
        __syncthreads();
        if (A1BF) {
            const u16* A1b = (const u16*)A1v;
            for (int idx = t; idx < 64 * (K1 / 4); idx += 256) {
                int node = idx / (K1 / 4), kq = (idx % (K1 / 4)) * 4;
                int gn = nb + node;
                s4v v = {0, 0, 0, 0};
                if (gn < NN) {
                    v = *(const s4v*)(A1b + (size_t)gn * K1 + kq);
                    if (AAFF) {
#pragma unroll
                        for (int i = 0; i < 4; i++) {
                            float f = b2f((u16)v[i]) * aaff[kq + i] + aaff[64 + kq + i];
                            v[i] = (short)f2b(f);
                        }
                    }
                }
                *(s4v*)&A_lds[node * KP + kq] = v;
            }
        } else {
            const float* A1f = (const float*)A1v;
            for (int idx = t; idx < 64 * (K1 / 4); idx += 256) {
                int node = idx / (K1 / 4), kq = (idx % (K1 / 4)) * 4;
                int gn = nb + node;
                s4v v = {0, 0, 0, 0};
                if (gn < NN) {
                    float4 a = ld4(A1f + (size_t)gn * K1 + kq);
                    v[0] = (short)f2b(a.x); v[1] = (short)f2b(a.y);
                    v[2] = (short)f2b(a.z); v[3] = (short)f2b(a.w);
                }
                *(s4v*)&A_lds[node * KP + kq] = v;
            }
        }
        if (K2 > 0) {
            for (int idx = t; idx < 64 * (K2 / 4); idx += 256) {
                int node = idx / (K2 / 4), kq = (idx % (K2 / 4)) * 4;
                int gn = nb + node;
                s4v v = {0, 0, 0, 0};
                if (gn < NN) v = *(const s4v*)(A2 + (size_t)gn * K2 + kq);
                *(s4v*)&A_lds[node * KP + K1 + kq] = v;
            }
        }
        __syncthreads();

        f32x4 acc[4];
#pragma unroll
        for (int n = 0; n < 4; n++) acc[n] = (f32x4){0.f, 0.f, 0.f, 0.f};
        const int arow = 16 * wv + l15;
#pragma unroll
        for (int kk = 0; kk < K; kk += 32) {
            s4v alo = *(const s4v*)&A_lds[arow * KP + kk + lg * 4];
            s4v ahi = *(const s4v*)&A_lds[arow * KP + kk + lg * 4 + 16];
            bf16x8 a = __builtin_shufflevector(alo, ahi, 0, 1, 2, 3, 4, 5, 6, 7);
#pragma unroll
            for (int n = 0; n < 4; n++) {
                s4v wlo = *(const s4v*)&Wt_lds[(16 * n + l15) * KP + kk + lg * 4];
                s4v whi = *(const s4v*)&Wt_lds[(16 * n + l15) * KP + kk + lg * 4 + 16];
                bf16x8 b = __builtin_shufflevector(wlo, whi, 0, 1, 2, 3, 4, 5, 6, 7);
                acc[n] = __builtin_amdgcn_mfma_f32_16x16x32_bf16(a, b, acc[n], 0, 0, 0);
            }
        }

        float ss[4] = {0, 0, 0, 0}, sq2[4] = {0, 0, 0, 0};
#pragma unroll
        for (int r = 0; r < 4; r++) {
            int node = nb + 16 * wv + lg * 4 + r;
            if (node < NN) {
                float deg = BE ? (float)(row_ptr[node + 1] - row_ptr[node]) : 0.f;
                int nv = EMB ? nvi[node] : 0;
#pragma unroll
                for (int n = 0; n < 4; n++) {
                    int ch = 16 * n + l15;
                    float v = acc[n][r] + bias_c[n];
                    if (BE) v += deg * be_c[n];
                    if (EMB) v += emb[(size_t)nv * 64 + ch];
                    if (RESID) v += b2f(resid[(size_t)node * 64 + ch]) * rsc_c[n] + rsh_c[n];
                    v = fmaxf(v, 0.f);
                    Xb[(size_t)node * 64 + ch] = f2b(v);
                    ss[n] += v;
                    sq2[n] += v * v;
                }
            }
        }
#pragma unroll
        for (int n = 0; n < 4; n++) {
            float a = ss[n];
            a += __shfl_xor(a, 16);
            a += __shfl_xor(a, 32);
            float b = sq2[n];
            b += __shfl_xor(b, 16);
            b += __shfl_xor(b, 32);
            if (lg == 0) {
                atomicAdd(&red[16 * n + l15], a);
                atomicAdd(&red[64 + 16 * n + l15], b);
            }
        }
    }
    __syncthreads();
    if (t < 128) atomicAdd(&stats[t], red[t]);
}

// ---------------- BN finalize ----------------
__global__ void kfin(float* __restrict__ stats, const float* __restrict__ g,
                     const float* __restrict__ b, int slot) {
    int t = threadIdx.x;  // 64
    float mean = stats[t] * (1.0f / NN);
    float var = stats[64 + t] * (1.0f / NN) - mean * mean;
    float rstd = rsqrtf(fmaxf(var, 0.f) + EPSBN);
    float sc = g[t] * rstd;
    float* slotp = stats + 128 + slot * 128;
    slotp[t] = sc;
    slotp[64 + t] = b[t] - mean * sc;
    stats[t] = 0.f;
    stats[64 + t] = 0.f;
}

// ---------------- message passing over packed bf16 h ----------------
__global__ void kmsg_bf(const u32* __restrict__ h2, const int* __restrict__ row_ptr,
                        const int2* __restrict__ pair, const float* __restrict__ aff,
                        u32* __restrict__ agg) {
    int lane = threadIdx.x & 63;
    int wid = threadIdx.x >> 6;
    int w = lane & 31, half = lane >> 5;
    float sc0 = aff[2 * w], sc1 = aff[2 * w + 1];
    float sh0 = aff[64 + 2 * w], sh1 = aff[64 + 2 * w + 1];
    for (int n = blockIdx.x * 4 + wid; n < NN; n += gridDim.x * 4) {
        int e0 = row_ptr[n], e1 = row_ptr[n + 1];
        float a0 = 0.f, a1 = 0.f;
        int e = e0;
        for (; e + 16 <= e1; e += 16) {
            int s0 = pair[e + half].y, s1 = pair[e + 2 + half].y;
            int s2 = pair[e + 4 + half].y, s3 = pair[e + 6 + half].y;
            int s4 = pair[e + 8 + half].y, s5 = pair[e + 10 + half].y;
            int s6 = pair[e + 12 + half].y, s7 = pair[e + 14 + half].y;
            u32 u0 = h2[(size_t)s0 * 32 + w];
            u32 u1 = h2[(size_t)s1 * 32 + w];
            u32 u2 = h2[(size_t)s2 * 32 + w];
            u32 u3 = h2[(size_t)s3 * 32 + w];
            u32 u4 = h2[(size_t)s4 * 32 + w];
            u32 u5 = h2[(size_t)s5 * 32 + w];
            u32 u6 = h2[(size_t)s6 * 32 + w];
            u32 u7 = h2[(size_t)s7 * 32 + w];
            a0 += ((blo(u0) + blo(u1)) + (blo(u2) + blo(u3))) +
                  ((blo(u4) + blo(u5)) + (blo(u6) + blo(u7)));
            a1 += ((bhi(u0) + bhi(u1)) + (bhi(u2) + bhi(u3))) +
                  ((bhi(u4) + bhi(u5)) + (bhi(u6) + bhi(u7)));
        }
        for (; e + 8 <= e1; e += 8) {
            int s0 = pair[e + half].y, s1 = pair[e + 2 + half].y;
            int s2 = pair[e + 4 + half].y, s3 = pair[e + 6 + half].y;
            u32 u0 = h2[(size_t)s0 * 32 + w];
            u32 u1 = h2[(size_t)s1 * 32 + w];
            u32 u2 = h2[(size_t)s2 * 32 + w];
            u32 u3 = h2[(size_t)s3 * 32 + w];
            a0 += (blo(u0) + blo(u1)) + (blo(u2) + blo(u3));
            a1 += (bhi(u0) + bhi(u1)) + (bhi(u2) + bhi(u3));
        }
        for (; e < e1; e += 2) {
            if (e + half < e1) {
                u32 u = h2[(size_t)pair[e + half].y * 32 + w];
                a0 += blo(u);
                a1 += bhi(u);
            }
        }
        a0 += __shfl_xor(a0, 32);
        a1 += __shfl_xor(a1, 32);
        if (half == 0) {
            float deg = (float)(e1 - e0);
            u16 o0 = f2b(sc0 * a0 + deg * sh0);
            u16 o1 = f2b(sc1 * a1 + deg * sh1);
            agg[(size_t)n * 32 + w] = (u32)o0 | ((u32)o1 << 16);
        }
    }
}

// ---------------- segmented max readout ----------------
__device__ __forceinline__ unsigned fenc(float f) {
    unsigned u = __float_as_uint(f);
    return (u >> 31) ? ~u : (u | 0x80000000u);
}
__device__ __forceinline__ float fdec(unsigned k) {
    return (k >> 31) ? __uint_as_float(k ^ 0x80000000u) : __uint_as_float(~k);
}

__global__ void kinitpk(unsigned* __restrict__ pk) {
    int i = blockIdx.x * blockDim.x + threadIdx.x;
    if (i < GG * DD) pk[i] = 0x007FFFFFu;
}

__global__ void kread(const u16* __restrict__ h2, const int* __restrict__ gidx,
                      const float* __restrict__ aff, unsigned* __restrict__ pk) {
    int lane = threadIdx.x & 63;
    int wid = threadIdx.x >> 6;
    float sc = aff[lane], sh = aff[64 + lane];
    int gw = blockIdx.x * 4 + wid;
    int nw = gridDim.x * 4;
    int chunk = (NN + nw - 1) / nw;
    int lo = gw * chunk, hi = min(lo + chunk, NN);
    if (lo >= hi) return;
    int cur = gidx[lo];
    float acc = -INFINITY;
    for (int n = lo; n < hi; n++) {
        int g = gidx[n];
        if (g != cur) {
            atomicMax(&pk[cur * DD + lane], fenc(acc));
            cur = g;
            acc = -INFINITY;
        }
        acc = fmaxf(acc, b2f(h2[(size_t)n * 64 + lane]) * sc + sh);
    }
    atomicMax(&pk[cur * DD + lane], fenc(acc));
}

__global__ void kout(const unsigned* __restrict__ pk, const float* __restrict__ W,
                     const float* __restrict__ b, float* __restrict__ out) {
    int t = blockIdx.x * blockDim.x + threadIdx.x;
    int g = t >> 6, d = t & 63;
    float acc = b[d];
    for (int k = 0; k < DD; k++) {
        float p = fdec(pk[g * DD + k]);
        acc += p * W[k * DD + d];
    }
    out[t] = fmaxf(acc, 0.f);
}

extern "C" void kernel_launch(void* const* d_in, const int* in_sizes, int n_in,
                              void* d_out, int out_size, void* d_ws, size_t ws_size,
                              hipStream_t stream) {
    const float* node_feat = (const float*)d_in[0];
    const float* edge_feat = (const float*)d_in[1];
    const float* w_n2l_W = (const float*)d_in[2];
    const float* w_n2l_b = (const float*)d_in[3];
    const float* nve = (const float*)d_in[4];
    const float* w_e2l_W = (const float*)d_in[5];
    const float* w_e2l_b = (const float*)d_in[6];
    const float* conv_W = (const float*)d_in[7];
    const float* conv_b = (const float*)d_in[8];
    const float* l2_W = (const float*)d_in[9];
    const float* l2_b = (const float*)d_in[10];
    const float* msg_g = (const float*)d_in[11];
    const float* msg_b = (const float*)d_in[12];
    const float* hid_g = (const float*)d_in[13];
    const float* hid_b = (const float*)d_in[14];
    const float* out_W = (const float*)d_in[15];
    const float* out_b = (const float*)d_in[16];
    const int* edge_from = (const int*)d_in[17];
    const int* edge_to = (const int*)d_in[18];
    const int* g_idx = (const int*)d_in[19];
    const int* nvi = (const int*)d_in[20];
    float* out = (float*)d_out;

    char* ws = (char*)d_ws;
    size_t off = 0;
    auto alloc = [&](size_t bytes) -> void* {
        void* p = ws + off;
        off += (bytes + 255) / 256 * 256;
        return p;
    };
    int* row_ptr = (int*)alloc((size_t)(NN + 1) * 4);
    int2* pair = (int2*)alloc((size_t)EE * 8);
    int2* tmp = (int2*)alloc((size_t)EE * 8);
    u16* pooled_ef = (u16*)alloc((size_t)NN * EF * 2);
    u16* h2a = (u16*)alloc((size_t)NN * DD * 2);
    u16* h2b = (u16*)alloc((size_t)NN * DD * 2);
    u16* agg_bf = (u16*)alloc((size_t)NN * DD * 2);
    u16* mb_bf = (u16*)alloc((size_t)NN * DD * 2);
    float* stats = (float*)alloc(1024 * 4);
    unsigned* pk = (unsigned*)alloc((size_t)GG * DD * 4);
    int* bhist = (int*)alloc((size_t)NBKT * 4);
    int* bbase = (int*)alloc((size_t)(NBKT + 1) * 4);
    int* gcur = (int*)alloc((size_t)NBKT * 4);
    (void)ws_size; (void)n_in; (void)in_sizes; (void)out_size;

    hipMemsetAsync(bhist, 0, (size_t)NBKT * 4, stream);
    hipMemsetAsync(stats, 0, 1024 * 4, stream);
    kinitpk<<<16, 256, 0, stream>>>(pk);

    k1b<<<256, 256, 0, stream>>>(edge_to, bhist);
    k1c<<<1, 512, 0, stream>>>(bhist, bbase, gcur);
    k1d<<<256, 256, 0, stream>>>(edge_to, edge_from, gcur, tmp);
    kp2<<<NBKT, 256, 0, stream>>>(tmp, bbase, row_ptr, pair);
    kpool<<<2048, 256, 0, stream>>>(edge_feat, row_ptr, pair, pooled_ef);

    const int GB = 782;

    // h0 -> h2a
    kgemm_mfma<NF, EF, false, false, true, true, false>
        <<<GB, 256, 0, stream>>>(node_feat, pooled_ef, w_n2l_W, w_e2l_W,
                                 w_n2l_b, w_e2l_b, row_ptr, nve, nvi,
                                 nullptr, nullptr, nullptr, h2a, stats);
    kfin<<<1, 64, 0, stream>>>(stats, msg_g, msg_b, 0);

    u16* hcur = h2a;
    u16* hnext = h2b;
    for (int lv = 0; lv < LVL; lv++) {
        kmsg_bf<<<2048, 256, 0, stream>>>((const u32*)hcur, row_ptr, pair,
                                          stats + 128 + lv * 128, (u32*)agg_bf);
        kgemm_mfma<DD, EF, true, false, false, true, false>
            <<<GB, 256, 0, stream>>>(agg_bf, pooled_ef, conv_W + lv * DD * DD,
                                     w_e2l_W + (size_t)(lv + 1) * EF * DD,
                                     conv_b + lv * DD,
                                     w_e2l_b + (size_t)(lv + 1) * DD, row_ptr,
                                     nullptr, nullptr, nullptr, nullptr, nullptr,
                                     mb_bf, stats);
        kfin<<<1, 64, 0, stream>>>(stats, hid_g + lv * DD, hid_b + lv * DD, 4 + lv);
        kgemm_mfma<DD, 0, true, true, false, false, true>
            <<<GB, 256, 0, stream>>>(mb_bf, nullptr, l2_W + lv * DD * DD, nullptr,
                                     l2_b + lv * DD, nullptr, row_ptr, nullptr,
                                     nullptr, hcur, stats + 128 + lv * 128,
                                     stats + 128 + (4 + lv) * 128, hnext, stats);
        kfin<<<1, 64, 0, stream>>>(stats, msg_g + (lv + 1) * DD, msg_b + (lv + 1) * DD,
                                   lv + 1);
        u16* tmp2 = hcur; hcur = hnext; hnext = tmp2;
    }

    kread<<<1024, 256, 0, stream>>>(hcur, g_idx, stats + 128 + LVL * 128, pk);
    kout<<<GG, 64, 0, stream>>>(pk, out_W, out_b, out);
}